// Round 9
// baseline (490.590 us; speedup 1.0000x reference)
//
#include <hip/hip_runtime.h>
#include <hip/hip_bf16.h>
#include <math.h>
#include <stdint.h>

#define N_NODES 50000
#define N_EDGES 800000
#define N_GRAPHS 256
#define F_IN 64
#define F_HID 128
#define N_HID 512
#define N_OUT 256

#define SCAN_B 256
#define SCAN_NBLK ((N_NODES + SCAN_B - 1) / SCAN_B)   // 196

// ---------------------------------------------------------------------------
// K1: in-degree count (edges only; self-loop added analytically later)
__global__ void count_deg(const int* __restrict__ ei, int* __restrict__ indeg) {
    int e = blockIdx.x * blockDim.x + threadIdx.x;
    if (e < N_EDGES) atomicAdd(&indeg[ei[N_EDGES + e]], 1);
}

// ---------------------------------------------------------------------------
// K2a: per-block reduction of indeg chunks -> blockSums
__global__ __launch_bounds__(SCAN_B) void scan_partial(const int* __restrict__ indeg,
                                                       int* __restrict__ blockSums) {
    __shared__ int sdata[SCAN_B];
    int i = blockIdx.x * SCAN_B + threadIdx.x;
    sdata[threadIdx.x] = (i < N_NODES) ? indeg[i] : 0;
    __syncthreads();
    for (int off = SCAN_B / 2; off > 0; off >>= 1) {
        if (threadIdx.x < off) sdata[threadIdx.x] += sdata[threadIdx.x + off];
        __syncthreads();
    }
    if (threadIdx.x == 0) blockSums[blockIdx.x] = sdata[0];
}

// K2b: single tiny block: exclusive scan of blockSums (SCAN_NBLK <= 256)
__global__ __launch_bounds__(SCAN_B) void scan_block_sums(int* __restrict__ blockSums) {
    __shared__ int buf[SCAN_B];
    int tid = threadIdx.x;
    int v = (tid < SCAN_NBLK) ? blockSums[tid] : 0;
    buf[tid] = v;
    __syncthreads();
    for (int off = 1; off < SCAN_B; off <<= 1) {
        int t = (tid >= off) ? buf[tid - off] : 0;
        __syncthreads();
        buf[tid] += t;
        __syncthreads();
    }
    if (tid < SCAN_NBLK) blockSums[tid] = buf[tid] - v;   // exclusive
}

// K2c: per-block exclusive scan + block offset -> offsets; also dis = rsqrt(deg+1)
__global__ __launch_bounds__(SCAN_B) void scan_final(const int* __restrict__ indeg,
                                                     const int* __restrict__ blockSums,
                                                     int* __restrict__ offsets,
                                                     float* __restrict__ dis) {
    __shared__ int buf[SCAN_B];
    int tid = threadIdx.x;
    int i = blockIdx.x * SCAN_B + tid;
    int v = (i < N_NODES) ? indeg[i] : 0;
    if (i < N_NODES) dis[i] = rsqrtf((float)(v + 1));
    buf[tid] = v;
    __syncthreads();
    for (int off = 1; off < SCAN_B; off <<= 1) {
        int t = (tid >= off) ? buf[tid - off] : 0;
        __syncthreads();
        buf[tid] += t;
        __syncthreads();
    }
    if (i < N_NODES) offsets[i] = blockSums[blockIdx.x] + buf[tid] - v;
    if (i == 0) offsets[N_NODES] = N_EDGES;   // total is statically known
}

// ---------------------------------------------------------------------------
// K3: scatter edges into CSR (by dst). Packed (src,w) -> one 8B store/edge.
__global__ void build_csr(const int* __restrict__ ei, const int* __restrict__ offsets,
                          int* __restrict__ cursor, const float* __restrict__ dis,
                          float2* __restrict__ csr) {
    int e = blockIdx.x * blockDim.x + threadIdx.x;
    if (e < N_EDGES) {
        int s = ei[e];
        int d = ei[N_EDGES + e];
        int pos = atomicAdd(&cursor[d], 1);
        csr[offsets[d] + pos] = make_float2(__int_as_float(s), dis[s] * dis[d]);
    }
}

// ---------------------------------------------------------------------------
// K4: C[M,128] = A[M,K] @ W[K,128]. 64x128 tile, 128 threads, 8x8/thread.
// A staged in LDS (8 b128/4k per wave = 96 cyc < VALU-share 128 -> VALU-bound).
// B is NOT staged: W is 64 KB, shared by all 782 blocks, L1/L2-resident —
// read fragments straight from global (different pipe than LDS).
template <int K, bool BIASRELU>
__global__ __launch_bounds__(128) void gemm8x8(const float* __restrict__ A,
                                               const float* __restrict__ W,
                                               const float* __restrict__ bias,
                                               float* __restrict__ out, int M) {
    const int BM = 64, KC = 32, LDA = 36;
    __shared__ float As[BM * LDA];     // 9.2 KB — only LDS in the kernel
    int tid = threadIdx.x;
    int tx = tid & 15;                 // cols tx*4 and 64+tx*4
    int ty = tid >> 4;                 // 0..7; rows ty + 8*i
    int row0 = blockIdx.x * BM;
    float acc[8][8] = {};
    for (int k0 = 0; k0 < K; k0 += KC) {
        // stage A: 4 float4 per thread (coalesced 128B row-chunks)
#pragma unroll
        for (int u = 0; u < 4; ++u) {
            int f4id = tid + 128 * u;
            int m = f4id >> 3;                 // 0..63
            int ks = (f4id & 7) * 4;           // 0,4,..28
            int r = row0 + m;
            float4 v = make_float4(0.f, 0.f, 0.f, 0.f);
            if (r < M) v = *(const float4*)&A[(size_t)r * K + k0 + ks];
            *(float4*)&As[m * LDA + ks] = v;
        }
        __syncthreads();
#pragma unroll
        for (int kc = 0; kc < KC; kc += 4) {
            float4 av[8], bv0[4], bv1[4];
#pragma unroll
            for (int i = 0; i < 8; ++i)
                av[i] = *(const float4*)&As[(ty + 8 * i) * LDA + kc];
#pragma unroll
            for (int q = 0; q < 4; ++q) {
                bv0[q] = *(const float4*)&W[(size_t)(k0 + kc + q) * 128 + tx * 4];
                bv1[q] = *(const float4*)&W[(size_t)(k0 + kc + q) * 128 + 64 + tx * 4];
            }
#pragma unroll
            for (int q = 0; q < 4; ++q) {
#pragma unroll
                for (int i = 0; i < 8; ++i) {
                    float a = ((const float*)&av[i])[q];
                    acc[i][0] += a * bv0[q].x;  acc[i][1] += a * bv0[q].y;
                    acc[i][2] += a * bv0[q].z;  acc[i][3] += a * bv0[q].w;
                    acc[i][4] += a * bv1[q].x;  acc[i][5] += a * bv1[q].y;
                    acc[i][6] += a * bv1[q].z;  acc[i][7] += a * bv1[q].w;
                }
            }
        }
        __syncthreads();
    }
    int c0 = tx * 4, c1 = 64 + tx * 4;
#pragma unroll
    for (int i = 0; i < 8; ++i) {
        int r = row0 + ty + 8 * i;
        if (r < M) {
            float4 v0 = make_float4(acc[i][0], acc[i][1], acc[i][2], acc[i][3]);
            float4 v1 = make_float4(acc[i][4], acc[i][5], acc[i][6], acc[i][7]);
            if (BIASRELU) {
                v0.x = fmaxf(v0.x + bias[c0], 0.f);   v0.y = fmaxf(v0.y + bias[c0+1], 0.f);
                v0.z = fmaxf(v0.z + bias[c0+2], 0.f); v0.w = fmaxf(v0.w + bias[c0+3], 0.f);
                v1.x = fmaxf(v1.x + bias[c1], 0.f);   v1.y = fmaxf(v1.y + bias[c1+1], 0.f);
                v1.z = fmaxf(v1.z + bias[c1+2], 0.f); v1.w = fmaxf(v1.w + bias[c1+3], 0.f);
            }
            *(float4*)&out[(size_t)r * 128 + c0] = v0;
            *(float4*)&out[(size_t)r * 128 + c1] = v1;
        }
    }
}

// ---------------------------------------------------------------------------
// K5a: F=128 aggregate, float4 lanes, 2 edges per gather instruction.
template <bool RELU>
__global__ __launch_bounds__(256) void aggregate128(const float* __restrict__ h,
                                                    const int* __restrict__ offsets,
                                                    const float2* __restrict__ csr,
                                                    const float* __restrict__ dis,
                                                    const float* __restrict__ bias,
                                                    float* __restrict__ out) {
    int wave = threadIdx.x >> 6;
    int lane = threadIdx.x & 63;
    int i = blockIdx.x * 4 + wave;
    if (i >= N_NODES) return;
    int sub = lane >> 5;               // which edge of the pair
    int q   = lane & 31;               // float4 index within the 128-f row
    const float4* h4 = (const float4*)h;   // row stride = 32 float4
    float4 acc = make_float4(0.f, 0.f, 0.f, 0.f);
    int j = offsets[i], s1 = offsets[i + 1];
    for (; j < s1; j += 16) {
        int s[8]; float w[8];
#pragma unroll
        for (int u = 0; u < 8; ++u) {
            int e = j + 2 * u + sub;
            float2 c = (e < s1) ? csr[e] : make_float2(__int_as_float(0), 0.f);
            s[u] = __float_as_int(c.x);
            w[u] = c.y;
        }
        float4 r[8];
#pragma unroll
        for (int u = 0; u < 8; ++u) r[u] = h4[(size_t)s[u] * 32 + q];
#pragma unroll
        for (int u = 0; u < 8; ++u) {
            acc.x += w[u] * r[u].x;  acc.y += w[u] * r[u].y;
            acc.z += w[u] * r[u].z;  acc.w += w[u] * r[u].w;
        }
    }
    acc.x += __shfl_xor(acc.x, 32, 64);
    acc.y += __shfl_xor(acc.y, 32, 64);
    acc.z += __shfl_xor(acc.z, 32, 64);
    acc.w += __shfl_xor(acc.w, 32, 64);
    float dii = dis[i];
    float4 self = h4[(size_t)i * 32 + q];
    float4 b = ((const float4*)bias)[q];
    acc.x += dii * dii * self.x + b.x;
    acc.y += dii * dii * self.y + b.y;
    acc.z += dii * dii * self.z + b.z;
    acc.w += dii * dii * self.w + b.w;
    if (RELU) {
        acc.x = fmaxf(acc.x, 0.f); acc.y = fmaxf(acc.y, 0.f);
        acc.z = fmaxf(acc.z, 0.f); acc.w = fmaxf(acc.w, 0.f);
    }
    if (sub == 0) ((float4*)out)[(size_t)i * 32 + q] = acc;
}

// K5b: F=64 aggregate of raw x (layer-0 reorder). float4 lanes, 4 edges/inst.
__global__ __launch_bounds__(256) void aggregate_x(const float* __restrict__ x,
                                                   const int* __restrict__ offsets,
                                                   const float2* __restrict__ csr,
                                                   const float* __restrict__ dis,
                                                   float* __restrict__ out) {
    int wave = threadIdx.x >> 6;
    int lane = threadIdx.x & 63;
    int i = blockIdx.x * 4 + wave;
    if (i >= N_NODES) return;
    int sub = lane >> 4;               // 0..3: which edge of the quad
    int q   = lane & 15;               // float4 index within the 64-f row
    const float4* x4 = (const float4*)x;   // row stride = 16 float4
    float4 acc = make_float4(0.f, 0.f, 0.f, 0.f);
    int j = offsets[i], s1 = offsets[i + 1];
    for (; j < s1; j += 16) {
        int s[4]; float w[4];
#pragma unroll
        for (int u = 0; u < 4; ++u) {
            int e = j + 4 * u + sub;
            float2 c = (e < s1) ? csr[e] : make_float2(__int_as_float(0), 0.f);
            s[u] = __float_as_int(c.x);
            w[u] = c.y;
        }
        float4 r[4];
#pragma unroll
        for (int u = 0; u < 4; ++u) r[u] = x4[(size_t)s[u] * 16 + q];
#pragma unroll
        for (int u = 0; u < 4; ++u) {
            acc.x += w[u] * r[u].x;  acc.y += w[u] * r[u].y;
            acc.z += w[u] * r[u].z;  acc.w += w[u] * r[u].w;
        }
    }
    acc.x += __shfl_xor(acc.x, 16, 64);
    acc.y += __shfl_xor(acc.y, 16, 64);
    acc.z += __shfl_xor(acc.z, 16, 64);
    acc.w += __shfl_xor(acc.w, 16, 64);
    acc.x += __shfl_xor(acc.x, 32, 64);
    acc.y += __shfl_xor(acc.y, 32, 64);
    acc.z += __shfl_xor(acc.z, 32, 64);
    acc.w += __shfl_xor(acc.w, 32, 64);
    float dii = dis[i];
    float4 self = x4[(size_t)i * 16 + q];
    acc.x += dii * dii * self.x;
    acc.y += dii * dii * self.y;
    acc.z += dii * dii * self.z;
    acc.w += dii * dii * self.w;
    if (sub == 0) ((float4*)out)[(size_t)i * 16 + q] = acc;
}

// ---------------------------------------------------------------------------
// K6: mean-pool (batch is sorted -> register-accumulate 16 nodes, flush on change)
__global__ __launch_bounds__(128) void pool16(const float* __restrict__ h,
                                              const int* __restrict__ batch,
                                              float* __restrict__ g_acc,
                                              float* __restrict__ g_cnt) {
    const int NB = 16;
    int base = blockIdx.x * NB;
    int f = threadIdx.x;
    float acc = 0.f;
    int cur = -1, cnt = 0;
    for (int n = 0; n < NB; ++n) {
        int i = base + n;
        if (i >= N_NODES) break;
        int b = batch[i];
        if (b != cur) {
            if (cur >= 0) {
                atomicAdd(&g_acc[(size_t)cur * F_HID + f], acc);
                if (f == 0) atomicAdd(&g_cnt[cur], (float)cnt);
            }
            cur = b; acc = 0.f; cnt = 0;
        }
        acc += h[(size_t)i * F_HID + f];
        cnt++;
    }
    if (cur >= 0) {
        atomicAdd(&g_acc[(size_t)cur * F_HID + f], acc);
        if (f == 0) atomicAdd(&g_cnt[cur], (float)cnt);
    }
}

// ---------------------------------------------------------------------------
// K7: g_hid = relu((g_acc/cnt) @ Wm1 + bm1)   [256,128]@[128,512]
__global__ __launch_bounds__(512) void mlp1(const float* __restrict__ g_acc,
                                            const float* __restrict__ g_cnt,
                                            const float* __restrict__ Wm1,
                                            const float* __restrict__ bm1,
                                            float* __restrict__ g_hid) {
    __shared__ float row[F_HID];
    int g = blockIdx.x;
    int t = threadIdx.x;              // 0..511
    if (t < F_HID) {
        float c = g_cnt[g];
        row[t] = g_acc[(size_t)g * F_HID + t] / fmaxf(c, 1.0f);
    }
    __syncthreads();
    float acc = bm1[t];
    for (int k = 0; k < F_HID; ++k) acc += row[k] * Wm1[(size_t)k * N_HID + t];
    g_hid[(size_t)g * N_HID + t] = fmaxf(acc, 0.f);
}

// K8: out = g_hid @ Wm2 + bm2   [256,512]@[512,256]
__global__ __launch_bounds__(256) void mlp2(const float* __restrict__ g_hid,
                                            const float* __restrict__ Wm2,
                                            const float* __restrict__ bm2,
                                            float* __restrict__ out) {
    __shared__ float row[N_HID];
    int g = blockIdx.x;
    int t = threadIdx.x;              // 0..255
    row[t] = g_hid[(size_t)g * N_HID + t];
    row[t + 256] = g_hid[(size_t)g * N_HID + t + 256];
    __syncthreads();
    float acc = bm2[t];
    for (int k = 0; k < N_HID; ++k) acc += row[k] * Wm2[(size_t)k * N_OUT + t];
    out[(size_t)g * N_OUT + t] = acc;
}

// ---------------------------------------------------------------------------
extern "C" void kernel_launch(void* const* d_in, const int* in_sizes, int n_in,
                              void* d_out, int out_size, void* d_ws, size_t ws_size,
                              hipStream_t stream) {
    const float* x   = (const float*)d_in[0];
    const int* ei    = (const int*)d_in[1];     // [2, E] int32
    const int* batch = (const int*)d_in[2];
    const float* W0 = (const float*)d_in[3];  const float* b0 = (const float*)d_in[4];
    const float* W1 = (const float*)d_in[5];  const float* b1 = (const float*)d_in[6];
    const float* W2 = (const float*)d_in[7];  const float* b2 = (const float*)d_in[8];
    const float* Wm1 = (const float*)d_in[9];  const float* bm1 = (const float*)d_in[10];
    const float* Wm2 = (const float*)d_in[11]; const float* bm2 = (const float*)d_in[12];

    // bump allocator on d_ws, 256B-aligned slots
    char* p = (char*)d_ws;
    auto alloc = [&](size_t bytes) -> char* {
        char* r = p;
        p += (bytes + 255) & ~(size_t)255;
        return r;
    };
    // zero-init region (contiguous in allocation order)
    int*   indeg  = (int*)alloc(N_NODES * 4);
    int*   cursor = (int*)alloc(N_NODES * 4);
    float* g_acc  = (float*)alloc((size_t)N_GRAPHS * F_HID * 4);
    float* g_cnt  = (float*)alloc(N_GRAPHS * 4);
    size_t zero_bytes = (size_t)(p - (char*)indeg);
    // rest
    int*   blockSums = (int*)alloc(SCAN_NBLK * 4);
    int*   offsets = (int*)alloc((N_NODES + 1) * 4);
    float* dis     = (float*)alloc(N_NODES * 4);
    float2* csr    = (float2*)alloc((size_t)N_EDGES * 8);
    float* ax      = (float*)alloc((size_t)N_NODES * F_IN * 4);
    float* h_a     = (float*)alloc((size_t)N_NODES * F_HID * 4);
    float* h_tmp   = (float*)alloc((size_t)N_NODES * F_HID * 4);
    float* h_b     = (float*)alloc((size_t)N_NODES * F_HID * 4);
    float* g_hid   = (float*)alloc((size_t)N_GRAPHS * N_HID * 4);
    (void)ws_size; (void)in_sizes; (void)n_in; (void)out_size;

    (void)hipMemsetAsync(indeg, 0, zero_bytes, stream);

    count_deg<<<(N_EDGES + 255) / 256, 256, 0, stream>>>(ei, indeg);
    scan_partial<<<SCAN_NBLK, SCAN_B, 0, stream>>>(indeg, blockSums);
    scan_block_sums<<<1, SCAN_B, 0, stream>>>(blockSums);
    scan_final<<<SCAN_NBLK, SCAN_B, 0, stream>>>(indeg, blockSums, offsets, dis);
    build_csr<<<(N_EDGES + 255) / 256, 256, 0, stream>>>(ei, offsets, cursor, dis, csr);

    int agg_grid = (N_NODES + 3) / 4;          // 4 nodes (waves) per block
    int gemm_grid = (N_NODES + 63) / 64;       // 782 blocks

    // layer 0 (reordered): ax = Â x; h_a = relu(ax @ W0 + b0)
    aggregate_x<<<agg_grid, 256, 0, stream>>>(x, offsets, csr, dis, ax);
    gemm8x8<F_IN, true><<<gemm_grid, 128, 0, stream>>>(ax, W0, b0, h_a, N_NODES);
    // layer 1: h_b = relu(Â (h_a @ W1) + b1)
    gemm8x8<F_HID, false><<<gemm_grid, 128, 0, stream>>>(h_a, W1, nullptr, h_tmp, N_NODES);
    aggregate128<true><<<agg_grid, 256, 0, stream>>>(h_tmp, offsets, csr, dis, b1, h_b);
    // layer 2: h_a = Â (h_b @ W2) + b2
    gemm8x8<F_HID, false><<<gemm_grid, 128, 0, stream>>>(h_b, W2, nullptr, h_tmp, N_NODES);
    aggregate128<false><<<agg_grid, 256, 0, stream>>>(h_tmp, offsets, csr, dis, b2, h_a);

    // pool + MLP
    pool16<<<(N_NODES + 15) / 16, 128, 0, stream>>>(h_a, batch, g_acc, g_cnt);
    mlp1<<<N_GRAPHS, N_HID, 0, stream>>>(g_acc, g_cnt, Wm1, bm1, g_hid);
    mlp2<<<N_GRAPHS, N_OUT, 0, stream>>>(g_hid, Wm2, bm2, (float*)d_out);
}

// Round 10
// 407.696 us; speedup vs baseline: 1.2033x; 1.2033x over previous
//
#include <hip/hip_runtime.h>
#include <hip/hip_bf16.h>
#include <math.h>
#include <stdint.h>

#define N_NODES 50000
#define N_EDGES 800000
#define N_GRAPHS 256
#define F_IN 64
#define F_HID 128
#define N_HID 512
#define N_OUT 256

#define SCAN_B 256
#define SCAN_NBLK ((N_NODES + SCAN_B - 1) / SCAN_B)   // 196

// ---------------------------------------------------------------------------
// K1: in-degree count (edges only; self-loop added analytically later)
__global__ void count_deg(const int* __restrict__ ei, int* __restrict__ indeg) {
    int e = blockIdx.x * blockDim.x + threadIdx.x;
    if (e < N_EDGES) atomicAdd(&indeg[ei[N_EDGES + e]], 1);
}

// ---------------------------------------------------------------------------
// K2a: per-block reduction of indeg chunks -> blockSums
__global__ __launch_bounds__(SCAN_B) void scan_partial(const int* __restrict__ indeg,
                                                       int* __restrict__ blockSums) {
    __shared__ int sdata[SCAN_B];
    int i = blockIdx.x * SCAN_B + threadIdx.x;
    sdata[threadIdx.x] = (i < N_NODES) ? indeg[i] : 0;
    __syncthreads();
    for (int off = SCAN_B / 2; off > 0; off >>= 1) {
        if (threadIdx.x < off) sdata[threadIdx.x] += sdata[threadIdx.x + off];
        __syncthreads();
    }
    if (threadIdx.x == 0) blockSums[blockIdx.x] = sdata[0];
}

// K2b: single tiny block: exclusive scan of blockSums (SCAN_NBLK <= 256)
__global__ __launch_bounds__(SCAN_B) void scan_block_sums(int* __restrict__ blockSums) {
    __shared__ int buf[SCAN_B];
    int tid = threadIdx.x;
    int v = (tid < SCAN_NBLK) ? blockSums[tid] : 0;
    buf[tid] = v;
    __syncthreads();
    for (int off = 1; off < SCAN_B; off <<= 1) {
        int t = (tid >= off) ? buf[tid - off] : 0;
        __syncthreads();
        buf[tid] += t;
        __syncthreads();
    }
    if (tid < SCAN_NBLK) blockSums[tid] = buf[tid] - v;   // exclusive
}

// K2c: per-block exclusive scan + block offset -> offsets; also dis = rsqrt(deg+1)
__global__ __launch_bounds__(SCAN_B) void scan_final(const int* __restrict__ indeg,
                                                     const int* __restrict__ blockSums,
                                                     int* __restrict__ offsets,
                                                     float* __restrict__ dis) {
    __shared__ int buf[SCAN_B];
    int tid = threadIdx.x;
    int i = blockIdx.x * SCAN_B + tid;
    int v = (i < N_NODES) ? indeg[i] : 0;
    if (i < N_NODES) dis[i] = rsqrtf((float)(v + 1));
    buf[tid] = v;
    __syncthreads();
    for (int off = 1; off < SCAN_B; off <<= 1) {
        int t = (tid >= off) ? buf[tid - off] : 0;
        __syncthreads();
        buf[tid] += t;
        __syncthreads();
    }
    if (i < N_NODES) offsets[i] = blockSums[blockIdx.x] + buf[tid] - v;
    if (i == 0) offsets[N_NODES] = N_EDGES;   // total is statically known
}

// ---------------------------------------------------------------------------
// K3: scatter edges into CSR (by dst). Packed (src,w) -> one 8B store/edge.
__global__ void build_csr(const int* __restrict__ ei, const int* __restrict__ offsets,
                          int* __restrict__ cursor, const float* __restrict__ dis,
                          float2* __restrict__ csr) {
    int e = blockIdx.x * blockDim.x + threadIdx.x;
    if (e < N_EDGES) {
        int s = ei[e];
        int d = ei[N_EDGES + e];
        int pos = atomicAdd(&cursor[d], 1);
        csr[offsets[d] + pos] = make_float2(__int_as_float(s), dis[s] * dis[d]);
    }
}

// ---------------------------------------------------------------------------
// K4: C[M, col0..col0+64) = A[M,K] @ W[K,128] tile. 64x64 tile, 128 threads,
// 8x4/thread, grid (782, 2) = 1564 blocks for occupancy (R9 showed the old
// 782-block grid capped waves/CU at ~6 -> latency-bound).
// All LDS reads b128; As row stride 36 keeps the 4-row broadcast conflict-free.
template <int K, bool BIASRELU>
__global__ __launch_bounds__(128) void gemm64(const float* __restrict__ A,
                                              const float* __restrict__ W,
                                              const float* __restrict__ bias,
                                              float* __restrict__ out, int M) {
    const int BM = 64, BN = 64, KC = 32, LDA = 36;
    __shared__ float As[BM * LDA];     // 9.2 KB
    __shared__ float Bs[KC * BN];      // 8 KB
    int tid = threadIdx.x;
    int tx = tid & 15;                 // cols col0 + tx*4
    int ty = tid >> 4;                 // 0..7; rows ty + 8*i
    int row0 = blockIdx.x * BM;
    int col0 = blockIdx.y * BN;
    float acc[8][4] = {};
    for (int k0 = 0; k0 < K; k0 += KC) {
        // stage A: 4 float4 per thread (coalesced 128B row-chunks)
#pragma unroll
        for (int u = 0; u < 4; ++u) {
            int f4id = tid + 128 * u;
            int m = f4id >> 3;                 // 0..63
            int ks = (f4id & 7) * 4;           // 0,4,..28
            int r = row0 + m;
            float4 v = make_float4(0.f, 0.f, 0.f, 0.f);
            if (r < M) v = *(const float4*)&A[(size_t)r * K + k0 + ks];
            *(float4*)&As[m * LDA + ks] = v;
        }
        // stage B: 4 float4 per thread
#pragma unroll
        for (int u = 0; u < 4; ++u) {
            int f4id = tid + 128 * u;
            int kk = f4id >> 4;                // 0..31
            int n4 = (f4id & 15) * 4;          // 0..60
            *(float4*)&Bs[kk * BN + n4] =
                *(const float4*)&W[(size_t)(k0 + kk) * 128 + col0 + n4];
        }
        __syncthreads();
#pragma unroll
        for (int kc = 0; kc < KC; kc += 4) {
            float4 av[8], bv[4];
#pragma unroll
            for (int i = 0; i < 8; ++i)
                av[i] = *(const float4*)&As[(ty + 8 * i) * LDA + kc];
#pragma unroll
            for (int q = 0; q < 4; ++q)
                bv[q] = *(const float4*)&Bs[(kc + q) * BN + tx * 4];
#pragma unroll
            for (int q = 0; q < 4; ++q) {
#pragma unroll
                for (int i = 0; i < 8; ++i) {
                    float a = ((const float*)&av[i])[q];
                    acc[i][0] += a * bv[q].x;  acc[i][1] += a * bv[q].y;
                    acc[i][2] += a * bv[q].z;  acc[i][3] += a * bv[q].w;
                }
            }
        }
        __syncthreads();
    }
    int c0 = col0 + tx * 4;
#pragma unroll
    for (int i = 0; i < 8; ++i) {
        int r = row0 + ty + 8 * i;
        if (r < M) {
            float4 v0 = make_float4(acc[i][0], acc[i][1], acc[i][2], acc[i][3]);
            if (BIASRELU) {
                v0.x = fmaxf(v0.x + bias[c0], 0.f);   v0.y = fmaxf(v0.y + bias[c0+1], 0.f);
                v0.z = fmaxf(v0.z + bias[c0+2], 0.f); v0.w = fmaxf(v0.w + bias[c0+3], 0.f);
            }
            *(float4*)&out[(size_t)r * 128 + c0] = v0;
        }
    }
}

// ---------------------------------------------------------------------------
// K5a: F=128 aggregate, float4 lanes, 2 edges per gather instruction.
// BIAS=false: raw Â·h (used for layer 2, where W2/b2 are applied post-pool).
template <bool RELU, bool BIAS>
__global__ __launch_bounds__(256) void aggregate128(const float* __restrict__ h,
                                                    const int* __restrict__ offsets,
                                                    const float2* __restrict__ csr,
                                                    const float* __restrict__ dis,
                                                    const float* __restrict__ bias,
                                                    float* __restrict__ out) {
    int wave = threadIdx.x >> 6;
    int lane = threadIdx.x & 63;
    int i = blockIdx.x * 4 + wave;
    if (i >= N_NODES) return;
    int sub = lane >> 5;               // which edge of the pair
    int q   = lane & 31;               // float4 index within the 128-f row
    const float4* h4 = (const float4*)h;   // row stride = 32 float4
    float4 acc = make_float4(0.f, 0.f, 0.f, 0.f);
    int j = offsets[i], s1 = offsets[i + 1];
    for (; j < s1; j += 16) {
        int s[8]; float w[8];
#pragma unroll
        for (int u = 0; u < 8; ++u) {
            int e = j + 2 * u + sub;
            float2 c = (e < s1) ? csr[e] : make_float2(__int_as_float(0), 0.f);
            s[u] = __float_as_int(c.x);
            w[u] = c.y;
        }
        float4 r[8];
#pragma unroll
        for (int u = 0; u < 8; ++u) r[u] = h4[(size_t)s[u] * 32 + q];
#pragma unroll
        for (int u = 0; u < 8; ++u) {
            acc.x += w[u] * r[u].x;  acc.y += w[u] * r[u].y;
            acc.z += w[u] * r[u].z;  acc.w += w[u] * r[u].w;
        }
    }
    acc.x += __shfl_xor(acc.x, 32, 64);
    acc.y += __shfl_xor(acc.y, 32, 64);
    acc.z += __shfl_xor(acc.z, 32, 64);
    acc.w += __shfl_xor(acc.w, 32, 64);
    float dii = dis[i];
    float4 self = h4[(size_t)i * 32 + q];
    acc.x += dii * dii * self.x;
    acc.y += dii * dii * self.y;
    acc.z += dii * dii * self.z;
    acc.w += dii * dii * self.w;
    if (BIAS) {
        float4 b = ((const float4*)bias)[q];
        acc.x += b.x; acc.y += b.y; acc.z += b.z; acc.w += b.w;
    }
    if (RELU) {
        acc.x = fmaxf(acc.x, 0.f); acc.y = fmaxf(acc.y, 0.f);
        acc.z = fmaxf(acc.z, 0.f); acc.w = fmaxf(acc.w, 0.f);
    }
    if (sub == 0) ((float4*)out)[(size_t)i * 32 + q] = acc;
}

// K5b: F=64 aggregate of raw x (layer-0 reorder). float4 lanes, 4 edges/inst.
__global__ __launch_bounds__(256) void aggregate_x(const float* __restrict__ x,
                                                   const int* __restrict__ offsets,
                                                   const float2* __restrict__ csr,
                                                   const float* __restrict__ dis,
                                                   float* __restrict__ out) {
    int wave = threadIdx.x >> 6;
    int lane = threadIdx.x & 63;
    int i = blockIdx.x * 4 + wave;
    if (i >= N_NODES) return;
    int sub = lane >> 4;               // 0..3: which edge of the quad
    int q   = lane & 15;               // float4 index within the 64-f row
    const float4* x4 = (const float4*)x;   // row stride = 16 float4
    float4 acc = make_float4(0.f, 0.f, 0.f, 0.f);
    int j = offsets[i], s1 = offsets[i + 1];
    for (; j < s1; j += 16) {
        int s[4]; float w[4];
#pragma unroll
        for (int u = 0; u < 4; ++u) {
            int e = j + 4 * u + sub;
            float2 c = (e < s1) ? csr[e] : make_float2(__int_as_float(0), 0.f);
            s[u] = __float_as_int(c.x);
            w[u] = c.y;
        }
        float4 r[4];
#pragma unroll
        for (int u = 0; u < 4; ++u) r[u] = x4[(size_t)s[u] * 16 + q];
#pragma unroll
        for (int u = 0; u < 4; ++u) {
            acc.x += w[u] * r[u].x;  acc.y += w[u] * r[u].y;
            acc.z += w[u] * r[u].z;  acc.w += w[u] * r[u].w;
        }
    }
    acc.x += __shfl_xor(acc.x, 16, 64);
    acc.y += __shfl_xor(acc.y, 16, 64);
    acc.z += __shfl_xor(acc.z, 16, 64);
    acc.w += __shfl_xor(acc.w, 16, 64);
    acc.x += __shfl_xor(acc.x, 32, 64);
    acc.y += __shfl_xor(acc.y, 32, 64);
    acc.z += __shfl_xor(acc.z, 32, 64);
    acc.w += __shfl_xor(acc.w, 32, 64);
    float dii = dis[i];
    float4 self = x4[(size_t)i * 16 + q];
    acc.x += dii * dii * self.x;
    acc.y += dii * dii * self.y;
    acc.z += dii * dii * self.z;
    acc.w += dii * dii * self.w;
    if (sub == 0) ((float4*)out)[(size_t)i * 16 + q] = acc;
}

// ---------------------------------------------------------------------------
// K6: mean-pool (batch is sorted -> register-accumulate 16 nodes, flush on change)
__global__ __launch_bounds__(128) void pool16(const float* __restrict__ h,
                                              const int* __restrict__ batch,
                                              float* __restrict__ g_acc,
                                              float* __restrict__ g_cnt) {
    const int NB = 16;
    int base = blockIdx.x * NB;
    int f = threadIdx.x;
    float acc = 0.f;
    int cur = -1, cnt = 0;
    for (int n = 0; n < NB; ++n) {
        int i = base + n;
        if (i >= N_NODES) break;
        int b = batch[i];
        if (b != cur) {
            if (cur >= 0) {
                atomicAdd(&g_acc[(size_t)cur * F_HID + f], acc);
                if (f == 0) atomicAdd(&g_cnt[cur], (float)cnt);
            }
            cur = b; acc = 0.f; cnt = 0;
        }
        acc += h[(size_t)i * F_HID + f];
        cnt++;
    }
    if (cur >= 0) {
        atomicAdd(&g_acc[(size_t)cur * F_HID + f], acc);
        if (f == 0) atomicAdd(&g_cnt[cur], (float)cnt);
    }
}

// ---------------------------------------------------------------------------
// K6b: g2 = (g_acc/cnt) @ W2 + b2   [256,128]@[128,128]  (layer-2 linear,
// commuted past aggregate+pool: pool(Â(hW2)+b2) == pool(Âh)W2 + b2)
__global__ __launch_bounds__(128) void graph_w2(const float* __restrict__ g_acc,
                                                const float* __restrict__ g_cnt,
                                                const float* __restrict__ W2,
                                                const float* __restrict__ b2,
                                                float* __restrict__ g2) {
    __shared__ float row[F_HID];
    int g = blockIdx.x;
    int t = threadIdx.x;              // 0..127
    float c = g_cnt[g];
    row[t] = g_acc[(size_t)g * F_HID + t] / fmaxf(c, 1.0f);
    __syncthreads();
    float acc = b2[t];
    for (int k = 0; k < F_HID; ++k) acc += row[k] * W2[(size_t)k * F_HID + t];
    g2[(size_t)g * F_HID + t] = acc;
}

// K7: g_hid = relu(g2 @ Wm1 + bm1)   [256,128]@[128,512]
__global__ __launch_bounds__(512) void mlp1(const float* __restrict__ g2,
                                            const float* __restrict__ Wm1,
                                            const float* __restrict__ bm1,
                                            float* __restrict__ g_hid) {
    __shared__ float row[F_HID];
    int g = blockIdx.x;
    int t = threadIdx.x;              // 0..511
    if (t < F_HID) row[t] = g2[(size_t)g * F_HID + t];
    __syncthreads();
    float acc = bm1[t];
    for (int k = 0; k < F_HID; ++k) acc += row[k] * Wm1[(size_t)k * N_HID + t];
    g_hid[(size_t)g * N_HID + t] = fmaxf(acc, 0.f);
}

// K8: out = g_hid @ Wm2 + bm2   [256,512]@[512,256]
__global__ __launch_bounds__(256) void mlp2(const float* __restrict__ g_hid,
                                            const float* __restrict__ Wm2,
                                            const float* __restrict__ bm2,
                                            float* __restrict__ out) {
    __shared__ float row[N_HID];
    int g = blockIdx.x;
    int t = threadIdx.x;              // 0..255
    row[t] = g_hid[(size_t)g * N_HID + t];
    row[t + 256] = g_hid[(size_t)g * N_HID + t + 256];
    __syncthreads();
    float acc = bm2[t];
    for (int k = 0; k < N_HID; ++k) acc += row[k] * Wm2[(size_t)k * N_OUT + t];
    out[(size_t)g * N_OUT + t] = acc;
}

// ---------------------------------------------------------------------------
extern "C" void kernel_launch(void* const* d_in, const int* in_sizes, int n_in,
                              void* d_out, int out_size, void* d_ws, size_t ws_size,
                              hipStream_t stream) {
    const float* x   = (const float*)d_in[0];
    const int* ei    = (const int*)d_in[1];     // [2, E] int32
    const int* batch = (const int*)d_in[2];
    const float* W0 = (const float*)d_in[3];  const float* b0 = (const float*)d_in[4];
    const float* W1 = (const float*)d_in[5];  const float* b1 = (const float*)d_in[6];
    const float* W2 = (const float*)d_in[7];  const float* b2 = (const float*)d_in[8];
    const float* Wm1 = (const float*)d_in[9];  const float* bm1 = (const float*)d_in[10];
    const float* Wm2 = (const float*)d_in[11]; const float* bm2 = (const float*)d_in[12];

    // bump allocator on d_ws, 256B-aligned slots
    char* p = (char*)d_ws;
    auto alloc = [&](size_t bytes) -> char* {
        char* r = p;
        p += (bytes + 255) & ~(size_t)255;
        return r;
    };
    // zero-init region (contiguous in allocation order)
    int*   indeg  = (int*)alloc(N_NODES * 4);
    int*   cursor = (int*)alloc(N_NODES * 4);
    float* g_acc  = (float*)alloc((size_t)N_GRAPHS * F_HID * 4);
    float* g_cnt  = (float*)alloc(N_GRAPHS * 4);
    size_t zero_bytes = (size_t)(p - (char*)indeg);
    // rest
    int*   blockSums = (int*)alloc(SCAN_NBLK * 4);
    int*   offsets = (int*)alloc((N_NODES + 1) * 4);
    float* dis     = (float*)alloc(N_NODES * 4);
    float2* csr    = (float2*)alloc((size_t)N_EDGES * 8);
    float* ax      = (float*)alloc((size_t)N_NODES * F_IN * 4);
    float* h_a     = (float*)alloc((size_t)N_NODES * F_HID * 4);
    float* h_tmp   = (float*)alloc((size_t)N_NODES * F_HID * 4);
    float* h_b     = (float*)alloc((size_t)N_NODES * F_HID * 4);
    float* g2      = (float*)alloc((size_t)N_GRAPHS * F_HID * 4);
    float* g_hid   = (float*)alloc((size_t)N_GRAPHS * N_HID * 4);
    (void)ws_size; (void)in_sizes; (void)n_in; (void)out_size;

    (void)hipMemsetAsync(indeg, 0, zero_bytes, stream);

    count_deg<<<(N_EDGES + 255) / 256, 256, 0, stream>>>(ei, indeg);
    scan_partial<<<SCAN_NBLK, SCAN_B, 0, stream>>>(indeg, blockSums);
    scan_block_sums<<<1, SCAN_B, 0, stream>>>(blockSums);
    scan_final<<<SCAN_NBLK, SCAN_B, 0, stream>>>(indeg, blockSums, offsets, dis);
    build_csr<<<(N_EDGES + 255) / 256, 256, 0, stream>>>(ei, offsets, cursor, dis, csr);

    int agg_grid = (N_NODES + 3) / 4;          // 4 nodes (waves) per block
    dim3 gemm_grid((N_NODES + 63) / 64, 2);    // 1564 blocks

    // layer 0 (reordered): ax = Â x; h_a = relu(ax @ W0 + b0)
    aggregate_x<<<agg_grid, 256, 0, stream>>>(x, offsets, csr, dis, ax);
    gemm64<F_IN, true><<<gemm_grid, 128, 0, stream>>>(ax, W0, b0, h_a, N_NODES);
    // layer 1: h_b = relu(Â (h_a @ W1) + b1)
    gemm64<F_HID, false><<<gemm_grid, 128, 0, stream>>>(h_a, W1, nullptr, h_tmp, N_NODES);
    aggregate128<true, true><<<agg_grid, 256, 0, stream>>>(h_tmp, offsets, csr, dis, b1, h_b);
    // layer 2 (commuted): a2 = Â h_b; pool; then (pool)@W2 + b2
    aggregate128<false, false><<<agg_grid, 256, 0, stream>>>(h_b, offsets, csr, dis, nullptr, h_a);

    // pool + layer-2 linear + MLP
    pool16<<<(N_NODES + 15) / 16, 128, 0, stream>>>(h_a, batch, g_acc, g_cnt);
    graph_w2<<<N_GRAPHS, 128, 0, stream>>>(g_acc, g_cnt, W2, b2, g2);
    mlp1<<<N_GRAPHS, N_HID, 0, stream>>>(g2, Wm1, bm1, g_hid);
    mlp2<<<N_GRAPHS, N_OUT, 0, stream>>>(g_hid, Wm2, bm2, (float*)d_out);
}

// Round 11
// 404.893 us; speedup vs baseline: 1.2117x; 1.0069x over previous
//
#include <hip/hip_runtime.h>
#include <hip/hip_bf16.h>
#include <math.h>
#include <stdint.h>

#define N_NODES 50000
#define N_EDGES 800000
#define N_GRAPHS 256
#define F_IN 64
#define F_HID 128
#define N_HID 512
#define N_OUT 256

#define SCAN_B 256
#define SCAN_NBLK ((N_NODES + SCAN_B - 1) / SCAN_B)   // 196

// pack two fp32 into a uint holding two bf16 (RNE); low16 = a, high16 = b
__device__ __forceinline__ unsigned int bf16pair(float a, float b) {
    unsigned int ua = __float_as_uint(a);
    unsigned int ub = __float_as_uint(b);
    ua += 0x7fffu + ((ua >> 16) & 1u);
    ub += 0x7fffu + ((ub >> 16) & 1u);
    return (ua >> 16) | (ub & 0xffff0000u);
}
// decode: f0 = low16 as bf16, f1 = high16
__device__ __forceinline__ float bf16lo(unsigned int u) { return __uint_as_float(u << 16); }
__device__ __forceinline__ float bf16hi(unsigned int u) { return __uint_as_float(u & 0xffff0000u); }

// ---------------------------------------------------------------------------
// K0: convert x (fp32) -> xb (bf16 pairs), 4 floats / thread
__global__ void cvt_bf16(const float* __restrict__ in, unsigned int* __restrict__ out, int n4) {
    int idx = blockIdx.x * blockDim.x + threadIdx.x;
    if (idx < n4) {
        float4 v = ((const float4*)in)[idx];
        ((uint2*)out)[idx] = make_uint2(bf16pair(v.x, v.y), bf16pair(v.z, v.w));
    }
}

// ---------------------------------------------------------------------------
// K1: in-degree count (edges only; self-loop added analytically later)
__global__ void count_deg(const int* __restrict__ ei, int* __restrict__ indeg) {
    int e = blockIdx.x * blockDim.x + threadIdx.x;
    if (e < N_EDGES) atomicAdd(&indeg[ei[N_EDGES + e]], 1);
}

// ---------------------------------------------------------------------------
// K2a: per-block reduction of indeg chunks -> blockSums
__global__ __launch_bounds__(SCAN_B) void scan_partial(const int* __restrict__ indeg,
                                                       int* __restrict__ blockSums) {
    __shared__ int sdata[SCAN_B];
    int i = blockIdx.x * SCAN_B + threadIdx.x;
    sdata[threadIdx.x] = (i < N_NODES) ? indeg[i] : 0;
    __syncthreads();
    for (int off = SCAN_B / 2; off > 0; off >>= 1) {
        if (threadIdx.x < off) sdata[threadIdx.x] += sdata[threadIdx.x + off];
        __syncthreads();
    }
    if (threadIdx.x == 0) blockSums[blockIdx.x] = sdata[0];
}

// K2b: single tiny block: exclusive scan of blockSums (SCAN_NBLK <= 256)
__global__ __launch_bounds__(SCAN_B) void scan_block_sums(int* __restrict__ blockSums) {
    __shared__ int buf[SCAN_B];
    int tid = threadIdx.x;
    int v = (tid < SCAN_NBLK) ? blockSums[tid] : 0;
    buf[tid] = v;
    __syncthreads();
    for (int off = 1; off < SCAN_B; off <<= 1) {
        int t = (tid >= off) ? buf[tid - off] : 0;
        __syncthreads();
        buf[tid] += t;
        __syncthreads();
    }
    if (tid < SCAN_NBLK) blockSums[tid] = buf[tid] - v;   // exclusive
}

// K2c: per-block exclusive scan + block offset -> offsets; also dis = rsqrt(deg+1)
__global__ __launch_bounds__(SCAN_B) void scan_final(const int* __restrict__ indeg,
                                                     const int* __restrict__ blockSums,
                                                     int* __restrict__ offsets,
                                                     float* __restrict__ dis) {
    __shared__ int buf[SCAN_B];
    int tid = threadIdx.x;
    int i = blockIdx.x * SCAN_B + tid;
    int v = (i < N_NODES) ? indeg[i] : 0;
    if (i < N_NODES) dis[i] = rsqrtf((float)(v + 1));
    buf[tid] = v;
    __syncthreads();
    for (int off = 1; off < SCAN_B; off <<= 1) {
        int t = (tid >= off) ? buf[tid - off] : 0;
        __syncthreads();
        buf[tid] += t;
        __syncthreads();
    }
    if (i < N_NODES) offsets[i] = blockSums[blockIdx.x] + buf[tid] - v;
    if (i == 0) offsets[N_NODES] = N_EDGES;   // total is statically known
}

// ---------------------------------------------------------------------------
// K3: scatter edges into CSR (by dst). Packed (src,w) -> one 8B store/edge.
__global__ void build_csr(const int* __restrict__ ei, const int* __restrict__ offsets,
                          int* __restrict__ cursor, const float* __restrict__ dis,
                          float2* __restrict__ csr) {
    int e = blockIdx.x * blockDim.x + threadIdx.x;
    if (e < N_EDGES) {
        int s = ei[e];
        int d = ei[N_EDGES + e];
        int pos = atomicAdd(&cursor[d], 1);
        csr[offsets[d] + pos] = make_float2(__int_as_float(s), dis[s] * dis[d]);
    }
}

// ---------------------------------------------------------------------------
// K4: C[M, col0..col0+64) = A[M,K] @ W[K,128] tile. 64x64 tile, 128 threads,
// 8x4/thread, grid (782, 2). BF16OUT: epilogue packs to bf16 (gather operand).
template <int K, bool BIASRELU, bool BF16OUT>
__global__ __launch_bounds__(128) void gemm64(const float* __restrict__ A,
                                              const float* __restrict__ W,
                                              const float* __restrict__ bias,
                                              void* __restrict__ outp, int M) {
    const int BM = 64, BN = 64, KC = 32, LDA = 36;
    __shared__ float As[BM * LDA];     // 9.2 KB
    __shared__ float Bs[KC * BN];      // 8 KB
    int tid = threadIdx.x;
    int tx = tid & 15;                 // cols col0 + tx*4
    int ty = tid >> 4;                 // 0..7; rows ty + 8*i
    int row0 = blockIdx.x * BM;
    int col0 = blockIdx.y * BN;
    float acc[8][4] = {};
    for (int k0 = 0; k0 < K; k0 += KC) {
#pragma unroll
        for (int u = 0; u < 4; ++u) {
            int f4id = tid + 128 * u;
            int m = f4id >> 3;                 // 0..63
            int ks = (f4id & 7) * 4;           // 0,4,..28
            int r = row0 + m;
            float4 v = make_float4(0.f, 0.f, 0.f, 0.f);
            if (r < M) v = *(const float4*)&A[(size_t)r * K + k0 + ks];
            *(float4*)&As[m * LDA + ks] = v;
        }
#pragma unroll
        for (int u = 0; u < 4; ++u) {
            int f4id = tid + 128 * u;
            int kk = f4id >> 4;                // 0..31
            int n4 = (f4id & 15) * 4;          // 0..60
            *(float4*)&Bs[kk * BN + n4] =
                *(const float4*)&W[(size_t)(k0 + kk) * 128 + col0 + n4];
        }
        __syncthreads();
#pragma unroll
        for (int kc = 0; kc < KC; kc += 4) {
            float4 av[8], bv[4];
#pragma unroll
            for (int i = 0; i < 8; ++i)
                av[i] = *(const float4*)&As[(ty + 8 * i) * LDA + kc];
#pragma unroll
            for (int q = 0; q < 4; ++q)
                bv[q] = *(const float4*)&Bs[(kc + q) * BN + tx * 4];
#pragma unroll
            for (int q = 0; q < 4; ++q) {
#pragma unroll
                for (int i = 0; i < 8; ++i) {
                    float a = ((const float*)&av[i])[q];
                    acc[i][0] += a * bv[q].x;  acc[i][1] += a * bv[q].y;
                    acc[i][2] += a * bv[q].z;  acc[i][3] += a * bv[q].w;
                }
            }
        }
        __syncthreads();
    }
    int c0 = col0 + tx * 4;
#pragma unroll
    for (int i = 0; i < 8; ++i) {
        int r = row0 + ty + 8 * i;
        if (r < M) {
            float4 v0 = make_float4(acc[i][0], acc[i][1], acc[i][2], acc[i][3]);
            if (BIASRELU) {
                v0.x = fmaxf(v0.x + bias[c0], 0.f);   v0.y = fmaxf(v0.y + bias[c0+1], 0.f);
                v0.z = fmaxf(v0.z + bias[c0+2], 0.f); v0.w = fmaxf(v0.w + bias[c0+3], 0.f);
            }
            if (BF16OUT) {
                uint2 o = make_uint2(bf16pair(v0.x, v0.y), bf16pair(v0.z, v0.w));
                ((uint2*)outp)[((size_t)r * 128 + c0) >> 2] = o;
            } else {
                *(float4*)&((float*)outp)[(size_t)r * 128 + c0] = v0;
            }
        }
    }
}

// ---------------------------------------------------------------------------
// K5a: F=128 aggregate over bf16 table. One wave per node; lane = feature
// pair (2q, 2q+1); one dword gather per edge per wave. fp32 accumulate.
template <bool RELU, bool BIAS, bool BF16OUT>
__global__ __launch_bounds__(256) void aggregate128b(const unsigned int* __restrict__ hb,
                                                     const int* __restrict__ offsets,
                                                     const float2* __restrict__ csr,
                                                     const float* __restrict__ dis,
                                                     const float* __restrict__ bias,
                                                     void* __restrict__ outp) {
    int wave = threadIdx.x >> 6;
    int lane = threadIdx.x & 63;              // uint index within 64-uint row
    int i = blockIdx.x * 4 + wave;
    if (i >= N_NODES) return;
    float a0 = 0.f, a1 = 0.f;
    int j = offsets[i], s1 = offsets[i + 1];
    for (; j < s1; j += 8) {
        int s[8]; float w[8];
#pragma unroll
        for (int u = 0; u < 8; ++u) {
            int e = j + u;
            float2 c = (e < s1) ? csr[e] : make_float2(__int_as_float(0), 0.f);
            s[u] = __float_as_int(c.x);
            w[u] = c.y;
        }
        unsigned int r[8];
#pragma unroll
        for (int u = 0; u < 8; ++u) r[u] = hb[(size_t)s[u] * 64 + lane];
#pragma unroll
        for (int u = 0; u < 8; ++u) {
            a0 += w[u] * bf16lo(r[u]);
            a1 += w[u] * bf16hi(r[u]);
        }
    }
    float dii = dis[i];
    unsigned int su = hb[(size_t)i * 64 + lane];
    a0 += dii * dii * bf16lo(su);
    a1 += dii * dii * bf16hi(su);
    if (BIAS) {
        float2 b = ((const float2*)bias)[lane];
        a0 += b.x; a1 += b.y;
    }
    if (RELU) { a0 = fmaxf(a0, 0.f); a1 = fmaxf(a1, 0.f); }
    if (BF16OUT) ((unsigned int*)outp)[(size_t)i * 64 + lane] = bf16pair(a0, a1);
    else         ((float2*)outp)[(size_t)i * 64 + lane] = make_float2(a0, a1);
}

// K5b: F=64 aggregate over bf16 x-table (layer-0 reorder). 2 edges/inst
// (lanes 0-31 edge A, 32-63 edge B); xor-32 combine; fp32 self from x.
__global__ __launch_bounds__(256) void aggregate_xb(const unsigned int* __restrict__ xb,
                                                    const float* __restrict__ x,
                                                    const int* __restrict__ offsets,
                                                    const float2* __restrict__ csr,
                                                    const float* __restrict__ dis,
                                                    float* __restrict__ out) {
    int wave = threadIdx.x >> 6;
    int lane = threadIdx.x & 63;
    int i = blockIdx.x * 4 + wave;
    if (i >= N_NODES) return;
    int sub = lane >> 5;              // which edge of the pair
    int q   = lane & 31;              // uint index within 32-uint row
    float a0 = 0.f, a1 = 0.f;
    int j = offsets[i], s1 = offsets[i + 1];
    for (; j < s1; j += 16) {
        int s[8]; float w[8];
#pragma unroll
        for (int u = 0; u < 8; ++u) {
            int e = j + 2 * u + sub;
            float2 c = (e < s1) ? csr[e] : make_float2(__int_as_float(0), 0.f);
            s[u] = __float_as_int(c.x);
            w[u] = c.y;
        }
        unsigned int r[8];
#pragma unroll
        for (int u = 0; u < 8; ++u) r[u] = xb[(size_t)s[u] * 32 + q];
#pragma unroll
        for (int u = 0; u < 8; ++u) {
            a0 += w[u] * bf16lo(r[u]);
            a1 += w[u] * bf16hi(r[u]);
        }
    }
    a0 += __shfl_xor(a0, 32, 64);
    a1 += __shfl_xor(a1, 32, 64);
    float dii = dis[i];
    float2 sx = ((const float2*)x)[(size_t)i * 32 + q];   // self in fp32
    a0 += dii * dii * sx.x;
    a1 += dii * dii * sx.y;
    if (sub == 0) ((float2*)out)[(size_t)i * 32 + q] = make_float2(a0, a1);
}

// ---------------------------------------------------------------------------
// K6: mean-pool (batch is sorted -> register-accumulate 16 nodes, flush on change)
__global__ __launch_bounds__(128) void pool16(const float* __restrict__ h,
                                              const int* __restrict__ batch,
                                              float* __restrict__ g_acc,
                                              float* __restrict__ g_cnt) {
    const int NB = 16;
    int base = blockIdx.x * NB;
    int f = threadIdx.x;
    float acc = 0.f;
    int cur = -1, cnt = 0;
    for (int n = 0; n < NB; ++n) {
        int i = base + n;
        if (i >= N_NODES) break;
        int b = batch[i];
        if (b != cur) {
            if (cur >= 0) {
                atomicAdd(&g_acc[(size_t)cur * F_HID + f], acc);
                if (f == 0) atomicAdd(&g_cnt[cur], (float)cnt);
            }
            cur = b; acc = 0.f; cnt = 0;
        }
        acc += h[(size_t)i * F_HID + f];
        cnt++;
    }
    if (cur >= 0) {
        atomicAdd(&g_acc[(size_t)cur * F_HID + f], acc);
        if (f == 0) atomicAdd(&g_cnt[cur], (float)cnt);
    }
}

// ---------------------------------------------------------------------------
// K6b: g2 = (g_acc/cnt) @ W2 + b2   [256,128]@[128,128]  (layer-2 linear,
// commuted past aggregate+pool: pool(Â(hW2)+b2) == pool(Âh)W2 + b2)
__global__ __launch_bounds__(128) void graph_w2(const float* __restrict__ g_acc,
                                                const float* __restrict__ g_cnt,
                                                const float* __restrict__ W2,
                                                const float* __restrict__ b2,
                                                float* __restrict__ g2) {
    __shared__ float row[F_HID];
    int g = blockIdx.x;
    int t = threadIdx.x;              // 0..127
    float c = g_cnt[g];
    row[t] = g_acc[(size_t)g * F_HID + t] / fmaxf(c, 1.0f);
    __syncthreads();
    float acc = b2[t];
    for (int k = 0; k < F_HID; ++k) acc += row[k] * W2[(size_t)k * F_HID + t];
    g2[(size_t)g * F_HID + t] = acc;
}

// K7: g_hid = relu(g2 @ Wm1 + bm1)   [256,128]@[128,512]
__global__ __launch_bounds__(512) void mlp1(const float* __restrict__ g2,
                                            const float* __restrict__ Wm1,
                                            const float* __restrict__ bm1,
                                            float* __restrict__ g_hid) {
    __shared__ float row[F_HID];
    int g = blockIdx.x;
    int t = threadIdx.x;              // 0..511
    if (t < F_HID) row[t] = g2[(size_t)g * F_HID + t];
    __syncthreads();
    float acc = bm1[t];
    for (int k = 0; k < F_HID; ++k) acc += row[k] * Wm1[(size_t)k * N_HID + t];
    g_hid[(size_t)g * N_HID + t] = fmaxf(acc, 0.f);
}

// K8: out = g_hid @ Wm2 + bm2   [256,512]@[512,256]
__global__ __launch_bounds__(256) void mlp2(const float* __restrict__ g_hid,
                                            const float* __restrict__ Wm2,
                                            const float* __restrict__ bm2,
                                            float* __restrict__ out) {
    __shared__ float row[N_HID];
    int g = blockIdx.x;
    int t = threadIdx.x;              // 0..255
    row[t] = g_hid[(size_t)g * N_HID + t];
    row[t + 256] = g_hid[(size_t)g * N_HID + t + 256];
    __syncthreads();
    float acc = bm2[t];
    for (int k = 0; k < N_HID; ++k) acc += row[k] * Wm2[(size_t)k * N_OUT + t];
    out[(size_t)g * N_OUT + t] = acc;
}

// ---------------------------------------------------------------------------
extern "C" void kernel_launch(void* const* d_in, const int* in_sizes, int n_in,
                              void* d_out, int out_size, void* d_ws, size_t ws_size,
                              hipStream_t stream) {
    const float* x   = (const float*)d_in[0];
    const int* ei    = (const int*)d_in[1];     // [2, E] int32
    const int* batch = (const int*)d_in[2];
    const float* W0 = (const float*)d_in[3];  const float* b0 = (const float*)d_in[4];
    const float* W1 = (const float*)d_in[5];  const float* b1 = (const float*)d_in[6];
    const float* W2 = (const float*)d_in[7];  const float* b2 = (const float*)d_in[8];
    const float* Wm1 = (const float*)d_in[9];  const float* bm1 = (const float*)d_in[10];
    const float* Wm2 = (const float*)d_in[11]; const float* bm2 = (const float*)d_in[12];

    // bump allocator on d_ws, 256B-aligned slots
    char* p = (char*)d_ws;
    auto alloc = [&](size_t bytes) -> char* {
        char* r = p;
        p += (bytes + 255) & ~(size_t)255;
        return r;
    };
    // zero-init region (contiguous in allocation order)
    int*   indeg  = (int*)alloc(N_NODES * 4);
    int*   cursor = (int*)alloc(N_NODES * 4);
    float* g_acc  = (float*)alloc((size_t)N_GRAPHS * F_HID * 4);
    float* g_cnt  = (float*)alloc(N_GRAPHS * 4);
    size_t zero_bytes = (size_t)(p - (char*)indeg);
    // rest
    int*   blockSums = (int*)alloc(SCAN_NBLK * 4);
    int*   offsets = (int*)alloc((N_NODES + 1) * 4);
    float* dis     = (float*)alloc(N_NODES * 4);
    float2* csr    = (float2*)alloc((size_t)N_EDGES * 8);
    unsigned int* xb     = (unsigned int*)alloc((size_t)N_NODES * F_IN / 2 * 4);   // bf16 x
    float*        ax     = (float*)alloc((size_t)N_NODES * F_IN * 4);
    float*        h_a    = (float*)alloc((size_t)N_NODES * F_HID * 4);
    unsigned int* h_tmpb = (unsigned int*)alloc((size_t)N_NODES * F_HID / 2 * 4);  // bf16
    unsigned int* h_bb   = (unsigned int*)alloc((size_t)N_NODES * F_HID / 2 * 4);  // bf16
    float*        agg2   = (float*)alloc((size_t)N_NODES * F_HID * 4);
    float*        g2     = (float*)alloc((size_t)N_GRAPHS * F_HID * 4);
    float*        g_hid  = (float*)alloc((size_t)N_GRAPHS * N_HID * 4);
    (void)ws_size; (void)in_sizes; (void)n_in; (void)out_size;

    (void)hipMemsetAsync(indeg, 0, zero_bytes, stream);

    cvt_bf16<<<(N_NODES * F_IN / 4 + 255) / 256, 256, 0, stream>>>(x, xb, N_NODES * F_IN / 4);
    count_deg<<<(N_EDGES + 255) / 256, 256, 0, stream>>>(ei, indeg);
    scan_partial<<<SCAN_NBLK, SCAN_B, 0, stream>>>(indeg, blockSums);
    scan_block_sums<<<1, SCAN_B, 0, stream>>>(blockSums);
    scan_final<<<SCAN_NBLK, SCAN_B, 0, stream>>>(indeg, blockSums, offsets, dis);
    build_csr<<<(N_EDGES + 255) / 256, 256, 0, stream>>>(ei, offsets, cursor, dis, csr);

    int agg_grid = (N_NODES + 3) / 4;          // 4 nodes (waves) per block
    dim3 gemm_grid((N_NODES + 63) / 64, 2);    // 1564 blocks

    // layer 0 (reordered): ax = Â x (bf16 gather); h_a = relu(ax @ W0 + b0)
    aggregate_xb<<<agg_grid, 256, 0, stream>>>(xb, x, offsets, csr, dis, ax);
    gemm64<F_IN, true, false><<<gemm_grid, 128, 0, stream>>>(ax, W0, b0, h_a, N_NODES);
    // layer 1: h_tmpb = bf16(h_a @ W1); h_bb = bf16(relu(Â h_tmpb + b1))
    gemm64<F_HID, false, true><<<gemm_grid, 128, 0, stream>>>(h_a, W1, nullptr, h_tmpb, N_NODES);
    aggregate128b<true, true, true><<<agg_grid, 256, 0, stream>>>(h_tmpb, offsets, csr, dis, b1, h_bb);
    // layer 2 (commuted): agg2 = Â h_bb (fp32 out); pool; then @W2 + b2
    aggregate128b<false, false, false><<<agg_grid, 256, 0, stream>>>(h_bb, offsets, csr, dis, nullptr, agg2);

    // pool + layer-2 linear + MLP
    pool16<<<(N_NODES + 15) / 16, 128, 0, stream>>>(agg2, batch, g_acc, g_cnt);
    graph_w2<<<N_GRAPHS, 128, 0, stream>>>(g_acc, g_cnt, W2, b2, g2);
    mlp1<<<N_GRAPHS, N_HID, 0, stream>>>(g2, Wm1, bm1, g_hid);
    mlp2<<<N_GRAPHS, N_OUT, 0, stream>>>(g_hid, Wm2, bm2, (float*)d_out);
}

// Round 12
// 378.747 us; speedup vs baseline: 1.2953x; 1.0690x over previous
//
#include <hip/hip_runtime.h>
#include <hip/hip_bf16.h>
#include <math.h>
#include <stdint.h>

#define N_NODES 50000
#define N_EDGES 800000
#define N_GRAPHS 256
#define F_IN 64
#define F_HID 128
#define N_HID 512
#define N_OUT 256

#define SCAN_B 256
#define SCAN_NBLK ((N_NODES + SCAN_B - 1) / SCAN_B)   // 196

// pack two fp32 into a uint holding two bf16 (RNE); low16 = a, high16 = b
__device__ __forceinline__ unsigned int bf16pair(float a, float b) {
    unsigned int ua = __float_as_uint(a);
    unsigned int ub = __float_as_uint(b);
    ua += 0x7fffu + ((ua >> 16) & 1u);
    ub += 0x7fffu + ((ub >> 16) & 1u);
    return (ua >> 16) | (ub & 0xffff0000u);
}
// decode: f0 = low16 as bf16, f1 = high16
__device__ __forceinline__ float bf16lo(unsigned int u) { return __uint_as_float(u << 16); }
__device__ __forceinline__ float bf16hi(unsigned int u) { return __uint_as_float(u & 0xffff0000u); }

// ---------------------------------------------------------------------------
// K0: convert x (fp32) -> xb (bf16 pairs), 4 floats / thread
__global__ void cvt_bf16(const float* __restrict__ in, unsigned int* __restrict__ out, int n4) {
    int idx = blockIdx.x * blockDim.x + threadIdx.x;
    if (idx < n4) {
        float4 v = ((const float4*)in)[idx];
        ((uint2*)out)[idx] = make_uint2(bf16pair(v.x, v.y), bf16pair(v.z, v.w));
    }
}

// ---------------------------------------------------------------------------
// K1: in-degree count (edges only; self-loop added analytically later)
__global__ void count_deg(const int* __restrict__ ei, int* __restrict__ indeg) {
    int e = blockIdx.x * blockDim.x + threadIdx.x;
    if (e < N_EDGES) atomicAdd(&indeg[ei[N_EDGES + e]], 1);
}

// ---------------------------------------------------------------------------
// K2a: per-block reduction of indeg chunks -> blockSums
__global__ __launch_bounds__(SCAN_B) void scan_partial(const int* __restrict__ indeg,
                                                       int* __restrict__ blockSums) {
    __shared__ int sdata[SCAN_B];
    int i = blockIdx.x * SCAN_B + threadIdx.x;
    sdata[threadIdx.x] = (i < N_NODES) ? indeg[i] : 0;
    __syncthreads();
    for (int off = SCAN_B / 2; off > 0; off >>= 1) {
        if (threadIdx.x < off) sdata[threadIdx.x] += sdata[threadIdx.x + off];
        __syncthreads();
    }
    if (threadIdx.x == 0) blockSums[blockIdx.x] = sdata[0];
}

// K2b: single tiny block: exclusive scan of blockSums (SCAN_NBLK <= 256)
__global__ __launch_bounds__(SCAN_B) void scan_block_sums(int* __restrict__ blockSums) {
    __shared__ int buf[SCAN_B];
    int tid = threadIdx.x;
    int v = (tid < SCAN_NBLK) ? blockSums[tid] : 0;
    buf[tid] = v;
    __syncthreads();
    for (int off = 1; off < SCAN_B; off <<= 1) {
        int t = (tid >= off) ? buf[tid - off] : 0;
        __syncthreads();
        buf[tid] += t;
        __syncthreads();
    }
    if (tid < SCAN_NBLK) blockSums[tid] = buf[tid] - v;   // exclusive
}

// K2c: per-block exclusive scan + block offset -> offsets; also dis = rsqrt(deg+1)
__global__ __launch_bounds__(SCAN_B) void scan_final(const int* __restrict__ indeg,
                                                     const int* __restrict__ blockSums,
                                                     int* __restrict__ offsets,
                                                     float* __restrict__ dis) {
    __shared__ int buf[SCAN_B];
    int tid = threadIdx.x;
    int i = blockIdx.x * SCAN_B + tid;
    int v = (i < N_NODES) ? indeg[i] : 0;
    if (i < N_NODES) dis[i] = rsqrtf((float)(v + 1));
    buf[tid] = v;
    __syncthreads();
    for (int off = 1; off < SCAN_B; off <<= 1) {
        int t = (tid >= off) ? buf[tid - off] : 0;
        __syncthreads();
        buf[tid] += t;
        __syncthreads();
    }
    if (i < N_NODES) offsets[i] = blockSums[blockIdx.x] + buf[tid] - v;
    if (i == 0) offsets[N_NODES] = N_EDGES;   // total is statically known
}

// ---------------------------------------------------------------------------
// K3: scatter edges into CSR (by dst). Packed (src,w) -> one 8B store/edge.
__global__ void build_csr(const int* __restrict__ ei, const int* __restrict__ offsets,
                          int* __restrict__ cursor, const float* __restrict__ dis,
                          float2* __restrict__ csr) {
    int e = blockIdx.x * blockDim.x + threadIdx.x;
    if (e < N_EDGES) {
        int s = ei[e];
        int d = ei[N_EDGES + e];
        int pos = atomicAdd(&cursor[d], 1);
        csr[offsets[d] + pos] = make_float2(__int_as_float(s), dis[s] * dis[d]);
    }
}

// ---------------------------------------------------------------------------
// K4: C[M, col0..col0+64) = A[M,K] @ W[K,128] tile. 64x64 tile, 128 threads,
// 8x4/thread, grid (782, 2). BF16OUT: epilogue packs to bf16 (gather operand).
template <int K, bool BIASRELU, bool BF16OUT>
__global__ __launch_bounds__(128) void gemm64(const float* __restrict__ A,
                                              const float* __restrict__ W,
                                              const float* __restrict__ bias,
                                              void* __restrict__ outp, int M) {
    const int BM = 64, BN = 64, KC = 32, LDA = 36;
    __shared__ float As[BM * LDA];     // 9.2 KB
    __shared__ float Bs[KC * BN];      // 8 KB
    int tid = threadIdx.x;
    int tx = tid & 15;                 // cols col0 + tx*4
    int ty = tid >> 4;                 // 0..7; rows ty + 8*i
    int row0 = blockIdx.x * BM;
    int col0 = blockIdx.y * BN;
    float acc[8][4] = {};
    for (int k0 = 0; k0 < K; k0 += KC) {
#pragma unroll
        for (int u = 0; u < 4; ++u) {
            int f4id = tid + 128 * u;
            int m = f4id >> 3;                 // 0..63
            int ks = (f4id & 7) * 4;           // 0,4,..28
            int r = row0 + m;
            float4 v = make_float4(0.f, 0.f, 0.f, 0.f);
            if (r < M) v = *(const float4*)&A[(size_t)r * K + k0 + ks];
            *(float4*)&As[m * LDA + ks] = v;
        }
#pragma unroll
        for (int u = 0; u < 4; ++u) {
            int f4id = tid + 128 * u;
            int kk = f4id >> 4;                // 0..31
            int n4 = (f4id & 15) * 4;          // 0..60
            *(float4*)&Bs[kk * BN + n4] =
                *(const float4*)&W[(size_t)(k0 + kk) * 128 + col0 + n4];
        }
        __syncthreads();
#pragma unroll
        for (int kc = 0; kc < KC; kc += 4) {
            float4 av[8], bv[4];
#pragma unroll
            for (int i = 0; i < 8; ++i)
                av[i] = *(const float4*)&As[(ty + 8 * i) * LDA + kc];
#pragma unroll
            for (int q = 0; q < 4; ++q)
                bv[q] = *(const float4*)&Bs[(kc + q) * BN + tx * 4];
#pragma unroll
            for (int q = 0; q < 4; ++q) {
#pragma unroll
                for (int i = 0; i < 8; ++i) {
                    float a = ((const float*)&av[i])[q];
                    acc[i][0] += a * bv[q].x;  acc[i][1] += a * bv[q].y;
                    acc[i][2] += a * bv[q].z;  acc[i][3] += a * bv[q].w;
                }
            }
        }
        __syncthreads();
    }
    int c0 = col0 + tx * 4;
#pragma unroll
    for (int i = 0; i < 8; ++i) {
        int r = row0 + ty + 8 * i;
        if (r < M) {
            float4 v0 = make_float4(acc[i][0], acc[i][1], acc[i][2], acc[i][3]);
            if (BIASRELU) {
                v0.x = fmaxf(v0.x + bias[c0], 0.f);   v0.y = fmaxf(v0.y + bias[c0+1], 0.f);
                v0.z = fmaxf(v0.z + bias[c0+2], 0.f); v0.w = fmaxf(v0.w + bias[c0+3], 0.f);
            }
            if (BF16OUT) {
                uint2 o = make_uint2(bf16pair(v0.x, v0.y), bf16pair(v0.z, v0.w));
                ((uint2*)outp)[((size_t)r * 128 + c0) >> 2] = o;
            } else {
                *(float4*)&((float*)outp)[(size_t)r * 128 + c0] = v0;
            }
        }
    }
}

// ---------------------------------------------------------------------------
// K5a: F=128 aggregate over bf16 table. uint2 lanes: 32 lanes cover a 256B
// row -> TWO edges per gather instruction, 16 edges in flight per wave.
// xor-32 shuffle combines the halves. fp32 accumulate.
template <bool RELU, bool BIAS, bool BF16OUT>
__global__ __launch_bounds__(256) void aggregate128b(const uint2* __restrict__ hb2,
                                                     const int* __restrict__ offsets,
                                                     const float2* __restrict__ csr,
                                                     const float* __restrict__ dis,
                                                     const float* __restrict__ bias,
                                                     void* __restrict__ outp) {
    int wave = threadIdx.x >> 6;
    int lane = threadIdx.x & 63;
    int i = blockIdx.x * 4 + wave;
    if (i >= N_NODES) return;
    int sub = lane >> 5;              // which edge of the pair
    int q   = lane & 31;              // uint2 index within the 32-uint2 row
    float a0 = 0.f, a1 = 0.f, a2 = 0.f, a3 = 0.f;
    int j = offsets[i], s1 = offsets[i + 1];
    for (; j < s1; j += 16) {
        int s[8]; float w[8];
#pragma unroll
        for (int u = 0; u < 8; ++u) {
            int e = j + 2 * u + sub;
            float2 c = (e < s1) ? csr[e] : make_float2(__int_as_float(0), 0.f);
            s[u] = __float_as_int(c.x);
            w[u] = c.y;
        }
        uint2 r[8];
#pragma unroll
        for (int u = 0; u < 8; ++u) r[u] = hb2[(size_t)s[u] * 32 + q];
#pragma unroll
        for (int u = 0; u < 8; ++u) {
            a0 += w[u] * bf16lo(r[u].x);
            a1 += w[u] * bf16hi(r[u].x);
            a2 += w[u] * bf16lo(r[u].y);
            a3 += w[u] * bf16hi(r[u].y);
        }
    }
    a0 += __shfl_xor(a0, 32, 64);
    a1 += __shfl_xor(a1, 32, 64);
    a2 += __shfl_xor(a2, 32, 64);
    a3 += __shfl_xor(a3, 32, 64);
    float dii = dis[i];
    uint2 su = hb2[(size_t)i * 32 + q];
    a0 += dii * dii * bf16lo(su.x);
    a1 += dii * dii * bf16hi(su.x);
    a2 += dii * dii * bf16lo(su.y);
    a3 += dii * dii * bf16hi(su.y);
    if (BIAS) {
        float4 b = ((const float4*)bias)[q];    // features 4q..4q+3
        a0 += b.x; a1 += b.y; a2 += b.z; a3 += b.w;
    }
    if (RELU) {
        a0 = fmaxf(a0, 0.f); a1 = fmaxf(a1, 0.f);
        a2 = fmaxf(a2, 0.f); a3 = fmaxf(a3, 0.f);
    }
    if (sub == 0) {
        if (BF16OUT)
            ((uint2*)outp)[(size_t)i * 32 + q] = make_uint2(bf16pair(a0, a1), bf16pair(a2, a3));
        else
            ((float4*)outp)[(size_t)i * 32 + q] = make_float4(a0, a1, a2, a3);
    }
}

// K5b: F=64 aggregate over bf16 x-table (layer-0 reorder). uint2 lanes:
// 16 lanes per 128B row -> FOUR edges per gather inst, 32 in flight.
// xor-16 + xor-32 combine; self read from fp32 x.
__global__ __launch_bounds__(256) void aggregate_xb(const uint2* __restrict__ xb2,
                                                    const float* __restrict__ x,
                                                    const int* __restrict__ offsets,
                                                    const float2* __restrict__ csr,
                                                    const float* __restrict__ dis,
                                                    float* __restrict__ out) {
    int wave = threadIdx.x >> 6;
    int lane = threadIdx.x & 63;
    int i = blockIdx.x * 4 + wave;
    if (i >= N_NODES) return;
    int sub = lane >> 4;              // 0..3: which edge of the quad
    int q   = lane & 15;              // uint2 index within the 16-uint2 row
    float a0 = 0.f, a1 = 0.f, a2 = 0.f, a3 = 0.f;
    int j = offsets[i], s1 = offsets[i + 1];
    for (; j < s1; j += 32) {
        int s[8]; float w[8];
#pragma unroll
        for (int u = 0; u < 8; ++u) {
            int e = j + 4 * u + sub;
            float2 c = (e < s1) ? csr[e] : make_float2(__int_as_float(0), 0.f);
            s[u] = __float_as_int(c.x);
            w[u] = c.y;
        }
        uint2 r[8];
#pragma unroll
        for (int u = 0; u < 8; ++u) r[u] = xb2[(size_t)s[u] * 16 + q];
#pragma unroll
        for (int u = 0; u < 8; ++u) {
            a0 += w[u] * bf16lo(r[u].x);
            a1 += w[u] * bf16hi(r[u].x);
            a2 += w[u] * bf16lo(r[u].y);
            a3 += w[u] * bf16hi(r[u].y);
        }
    }
    a0 += __shfl_xor(a0, 16, 64);  a1 += __shfl_xor(a1, 16, 64);
    a2 += __shfl_xor(a2, 16, 64);  a3 += __shfl_xor(a3, 16, 64);
    a0 += __shfl_xor(a0, 32, 64);  a1 += __shfl_xor(a1, 32, 64);
    a2 += __shfl_xor(a2, 32, 64);  a3 += __shfl_xor(a3, 32, 64);
    float dii = dis[i];
    float4 sx = ((const float4*)x)[(size_t)i * 16 + q];   // self in fp32
    a0 += dii * dii * sx.x;
    a1 += dii * dii * sx.y;
    a2 += dii * dii * sx.z;
    a3 += dii * dii * sx.w;
    if (sub == 0) ((float4*)out)[(size_t)i * 16 + q] = make_float4(a0, a1, a2, a3);
}

// ---------------------------------------------------------------------------
// K6: mean-pool (batch is sorted -> register-accumulate 16 nodes, flush on change)
__global__ __launch_bounds__(128) void pool16(const float* __restrict__ h,
                                              const int* __restrict__ batch,
                                              float* __restrict__ g_acc,
                                              float* __restrict__ g_cnt) {
    const int NB = 16;
    int base = blockIdx.x * NB;
    int f = threadIdx.x;
    float acc = 0.f;
    int cur = -1, cnt = 0;
    for (int n = 0; n < NB; ++n) {
        int i = base + n;
        if (i >= N_NODES) break;
        int b = batch[i];
        if (b != cur) {
            if (cur >= 0) {
                atomicAdd(&g_acc[(size_t)cur * F_HID + f], acc);
                if (f == 0) atomicAdd(&g_cnt[cur], (float)cnt);
            }
            cur = b; acc = 0.f; cnt = 0;
        }
        acc += h[(size_t)i * F_HID + f];
        cnt++;
    }
    if (cur >= 0) {
        atomicAdd(&g_acc[(size_t)cur * F_HID + f], acc);
        if (f == 0) atomicAdd(&g_cnt[cur], (float)cnt);
    }
}

// ---------------------------------------------------------------------------
// K6b: g2 = (g_acc/cnt) @ W2 + b2   [256,128]@[128,128]  (layer-2 linear,
// commuted past aggregate+pool: pool(Â(hW2)+b2) == pool(Âh)W2 + b2)
__global__ __launch_bounds__(128) void graph_w2(const float* __restrict__ g_acc,
                                                const float* __restrict__ g_cnt,
                                                const float* __restrict__ W2,
                                                const float* __restrict__ b2,
                                                float* __restrict__ g2) {
    __shared__ float row[F_HID];
    int g = blockIdx.x;
    int t = threadIdx.x;              // 0..127
    float c = g_cnt[g];
    row[t] = g_acc[(size_t)g * F_HID + t] / fmaxf(c, 1.0f);
    __syncthreads();
    float acc = b2[t];
    for (int k = 0; k < F_HID; ++k) acc += row[k] * W2[(size_t)k * F_HID + t];
    g2[(size_t)g * F_HID + t] = acc;
}

// K7: g_hid = relu(g2 @ Wm1 + bm1)   [256,128]@[128,512]
__global__ __launch_bounds__(512) void mlp1(const float* __restrict__ g2,
                                            const float* __restrict__ Wm1,
                                            const float* __restrict__ bm1,
                                            float* __restrict__ g_hid) {
    __shared__ float row[F_HID];
    int g = blockIdx.x;
    int t = threadIdx.x;              // 0..511
    if (t < F_HID) row[t] = g2[(size_t)g * F_HID + t];
    __syncthreads();
    float acc = bm1[t];
    for (int k = 0; k < F_HID; ++k) acc += row[k] * Wm1[(size_t)k * N_HID + t];
    g_hid[(size_t)g * N_HID + t] = fmaxf(acc, 0.f);
}

// K8: out = g_hid @ Wm2 + bm2   [256,512]@[512,256]
__global__ __launch_bounds__(256) void mlp2(const float* __restrict__ g_hid,
                                            const float* __restrict__ Wm2,
                                            const float* __restrict__ bm2,
                                            float* __restrict__ out) {
    __shared__ float row[N_HID];
    int g = blockIdx.x;
    int t = threadIdx.x;              // 0..255
    row[t] = g_hid[(size_t)g * N_HID + t];
    row[t + 256] = g_hid[(size_t)g * N_HID + t + 256];
    __syncthreads();
    float acc = bm2[t];
    for (int k = 0; k < N_HID; ++k) acc += row[k] * Wm2[(size_t)k * N_OUT + t];
    out[(size_t)g * N_OUT + t] = acc;
}

// ---------------------------------------------------------------------------
extern "C" void kernel_launch(void* const* d_in, const int* in_sizes, int n_in,
                              void* d_out, int out_size, void* d_ws, size_t ws_size,
                              hipStream_t stream) {
    const float* x   = (const float*)d_in[0];
    const int* ei    = (const int*)d_in[1];     // [2, E] int32
    const int* batch = (const int*)d_in[2];
    const float* W0 = (const float*)d_in[3];  const float* b0 = (const float*)d_in[4];
    const float* W1 = (const float*)d_in[5];  const float* b1 = (const float*)d_in[6];
    const float* W2 = (const float*)d_in[7];  const float* b2 = (const float*)d_in[8];
    const float* Wm1 = (const float*)d_in[9];  const float* bm1 = (const float*)d_in[10];
    const float* Wm2 = (const float*)d_in[11]; const float* bm2 = (const float*)d_in[12];

    // bump allocator on d_ws, 256B-aligned slots
    char* p = (char*)d_ws;
    auto alloc = [&](size_t bytes) -> char* {
        char* r = p;
        p += (bytes + 255) & ~(size_t)255;
        return r;
    };
    // zero-init region (contiguous in allocation order)
    int*   indeg  = (int*)alloc(N_NODES * 4);
    int*   cursor = (int*)alloc(N_NODES * 4);
    float* g_acc  = (float*)alloc((size_t)N_GRAPHS * F_HID * 4);
    float* g_cnt  = (float*)alloc(N_GRAPHS * 4);
    size_t zero_bytes = (size_t)(p - (char*)indeg);
    // rest
    int*   blockSums = (int*)alloc(SCAN_NBLK * 4);
    int*   offsets = (int*)alloc((N_NODES + 1) * 4);
    float* dis     = (float*)alloc(N_NODES * 4);
    float2* csr    = (float2*)alloc((size_t)N_EDGES * 8);
    unsigned int* xb     = (unsigned int*)alloc((size_t)N_NODES * F_IN / 2 * 4);   // bf16 x
    float*        ax     = (float*)alloc((size_t)N_NODES * F_IN * 4);
    float*        h_a    = (float*)alloc((size_t)N_NODES * F_HID * 4);
    unsigned int* h_tmpb = (unsigned int*)alloc((size_t)N_NODES * F_HID / 2 * 4);  // bf16
    unsigned int* h_bb   = (unsigned int*)alloc((size_t)N_NODES * F_HID / 2 * 4);  // bf16
    float*        agg2   = (float*)alloc((size_t)N_NODES * F_HID * 4);
    float*        g2     = (float*)alloc((size_t)N_GRAPHS * F_HID * 4);
    float*        g_hid  = (float*)alloc((size_t)N_GRAPHS * N_HID * 4);
    (void)ws_size; (void)in_sizes; (void)n_in; (void)out_size;

    (void)hipMemsetAsync(indeg, 0, zero_bytes, stream);

    cvt_bf16<<<(N_NODES * F_IN / 4 + 255) / 256, 256, 0, stream>>>(x, xb, N_NODES * F_IN / 4);
    count_deg<<<(N_EDGES + 255) / 256, 256, 0, stream>>>(ei, indeg);
    scan_partial<<<SCAN_NBLK, SCAN_B, 0, stream>>>(indeg, blockSums);
    scan_block_sums<<<1, SCAN_B, 0, stream>>>(blockSums);
    scan_final<<<SCAN_NBLK, SCAN_B, 0, stream>>>(indeg, blockSums, offsets, dis);
    build_csr<<<(N_EDGES + 255) / 256, 256, 0, stream>>>(ei, offsets, cursor, dis, csr);

    int agg_grid = (N_NODES + 3) / 4;          // 4 nodes (waves) per block
    dim3 gemm_grid((N_NODES + 63) / 64, 2);    // 1564 blocks

    // layer 0 (reordered): ax = Â x (bf16 gather); h_a = relu(ax @ W0 + b0)
    aggregate_xb<<<agg_grid, 256, 0, stream>>>((const uint2*)xb, x, offsets, csr, dis, ax);
    gemm64<F_IN, true, false><<<gemm_grid, 128, 0, stream>>>(ax, W0, b0, h_a, N_NODES);
    // layer 1: h_tmpb = bf16(h_a @ W1); h_bb = bf16(relu(Â h_tmpb + b1))
    gemm64<F_HID, false, true><<<gemm_grid, 128, 0, stream>>>(h_a, W1, nullptr, h_tmpb, N_NODES);
    aggregate128b<true, true, true><<<agg_grid, 256, 0, stream>>>((const uint2*)h_tmpb, offsets, csr, dis, b1, h_bb);
    // layer 2 (commuted): agg2 = Â h_bb (fp32 out); pool; then @W2 + b2
    aggregate128b<false, false, false><<<agg_grid, 256, 0, stream>>>((const uint2*)h_bb, offsets, csr, dis, nullptr, agg2);

    // pool + layer-2 linear + MLP
    pool16<<<(N_NODES + 15) / 16, 128, 0, stream>>>(agg2, batch, g_acc, g_cnt);
    graph_w2<<<N_GRAPHS, 128, 0, stream>>>(g_acc, g_cnt, W2, b2, g2);
    mlp1<<<N_GRAPHS, N_HID, 0, stream>>>(g2, Wm1, bm1, g_hid);
    mlp2<<<N_GRAPHS, N_OUT, 0, stream>>>(g_hid, Wm2, bm2, (float*)d_out);
}

// Round 13
// 370.674 us; speedup vs baseline: 1.3235x; 1.0218x over previous
//
#include <hip/hip_runtime.h>
#include <hip/hip_bf16.h>
#include <math.h>
#include <stdint.h>

#define N_NODES 50000
#define N_EDGES 800000
#define N_GRAPHS 256
#define F_IN 64
#define F_HID 128
#define N_HID 512
#define N_OUT 256

#define SCAN_B 256
#define SCAN_NBLK ((N_NODES + SCAN_B - 1) / SCAN_B)   // 196

// pack two fp32 into a uint holding two bf16 (RNE); low16 = a, high16 = b
__device__ __forceinline__ unsigned int bf16pair(float a, float b) {
    unsigned int ua = __float_as_uint(a);
    unsigned int ub = __float_as_uint(b);
    ua += 0x7fffu + ((ua >> 16) & 1u);
    ub += 0x7fffu + ((ub >> 16) & 1u);
    return (ua >> 16) | (ub & 0xffff0000u);
}
__device__ __forceinline__ float bf16lo(unsigned int u) { return __uint_as_float(u << 16); }
__device__ __forceinline__ float bf16hi(unsigned int u) { return __uint_as_float(u & 0xffff0000u); }

// ---------------------------------------------------------------------------
// K0: xb'[s] = bf16(dis[s] * x[s])  (pre-scaled gather table; runs after scan)
__global__ void cvt_bf16(const float* __restrict__ in, const float* __restrict__ dis,
                         unsigned int* __restrict__ out, int n4) {
    int idx = blockIdx.x * blockDim.x + threadIdx.x;
    if (idx < n4) {
        int node = idx >> 4;                  // 16 float4 per 64-f row
        float d = dis[node];
        float4 v = ((const float4*)in)[idx];
        ((uint2*)out)[idx] = make_uint2(bf16pair(d * v.x, d * v.y),
                                        bf16pair(d * v.z, d * v.w));
    }
}

// ---------------------------------------------------------------------------
// K1: in-degree count (edges only; self-loop added analytically later)
__global__ void count_deg(const int* __restrict__ ei, int* __restrict__ indeg) {
    int e = blockIdx.x * blockDim.x + threadIdx.x;
    if (e < N_EDGES) atomicAdd(&indeg[ei[N_EDGES + e]], 1);
}

// ---------------------------------------------------------------------------
// K2a: per-block reduction of indeg chunks -> blockSums
__global__ __launch_bounds__(SCAN_B) void scan_partial(const int* __restrict__ indeg,
                                                       int* __restrict__ blockSums) {
    __shared__ int sdata[SCAN_B];
    int i = blockIdx.x * SCAN_B + threadIdx.x;
    sdata[threadIdx.x] = (i < N_NODES) ? indeg[i] : 0;
    __syncthreads();
    for (int off = SCAN_B / 2; off > 0; off >>= 1) {
        if (threadIdx.x < off) sdata[threadIdx.x] += sdata[threadIdx.x + off];
        __syncthreads();
    }
    if (threadIdx.x == 0) blockSums[blockIdx.x] = sdata[0];
}

// K2b: single tiny block: exclusive scan of blockSums (SCAN_NBLK <= 256)
__global__ __launch_bounds__(SCAN_B) void scan_block_sums(int* __restrict__ blockSums) {
    __shared__ int buf[SCAN_B];
    int tid = threadIdx.x;
    int v = (tid < SCAN_NBLK) ? blockSums[tid] : 0;
    buf[tid] = v;
    __syncthreads();
    for (int off = 1; off < SCAN_B; off <<= 1) {
        int t = (tid >= off) ? buf[tid - off] : 0;
        __syncthreads();
        buf[tid] += t;
        __syncthreads();
    }
    if (tid < SCAN_NBLK) blockSums[tid] = buf[tid] - v;   // exclusive
}

// K2c: per-block exclusive scan + block offset -> offsets; also dis = rsqrt(deg+1)
__global__ __launch_bounds__(SCAN_B) void scan_final(const int* __restrict__ indeg,
                                                     const int* __restrict__ blockSums,
                                                     int* __restrict__ offsets,
                                                     float* __restrict__ dis) {
    __shared__ int buf[SCAN_B];
    int tid = threadIdx.x;
    int i = blockIdx.x * SCAN_B + tid;
    int v = (i < N_NODES) ? indeg[i] : 0;
    if (i < N_NODES) dis[i] = rsqrtf((float)(v + 1));
    buf[tid] = v;
    __syncthreads();
    for (int off = 1; off < SCAN_B; off <<= 1) {
        int t = (tid >= off) ? buf[tid - off] : 0;
        __syncthreads();
        buf[tid] += t;
        __syncthreads();
    }
    if (i < N_NODES) offsets[i] = blockSums[blockIdx.x] + buf[tid] - v;
    if (i == 0) offsets[N_NODES] = N_EDGES;   // total is statically known
}

// ---------------------------------------------------------------------------
// K3: scatter edges into CSR (by dst). Entry = ushort src (weights are folded
// into the pre-scaled tables) -> 2 B/edge, 4x fewer dirty-line bounces.
__global__ void build_csr(const int* __restrict__ ei, const int* __restrict__ offsets,
                          int* __restrict__ cursor, unsigned short* __restrict__ csr) {
    int e = blockIdx.x * blockDim.x + threadIdx.x;
    if (e < N_EDGES) {
        int s = ei[e];
        int d = ei[N_EDGES + e];
        int pos = atomicAdd(&cursor[d], 1);
        csr[offsets[d] + pos] = (unsigned short)s;
    }
}

// ---------------------------------------------------------------------------
// K4: C[M, col0..col0+64) = A[M,K] @ W[K,128] tile. 64x64 tile, 128 threads,
// 8x4/thread, grid (782, 2). BF16OUT: epilogue packs dis[r]-pre-scaled bf16.
template <int K, bool BIASRELU, bool BF16OUT>
__global__ __launch_bounds__(128) void gemm64(const float* __restrict__ A,
                                              const float* __restrict__ W,
                                              const float* __restrict__ bias,
                                              const float* __restrict__ disv,
                                              void* __restrict__ outp, int M) {
    const int BM = 64, BN = 64, KC = 32, LDA = 36;
    __shared__ float As[BM * LDA];     // 9.2 KB
    __shared__ float Bs[KC * BN];      // 8 KB
    int tid = threadIdx.x;
    int tx = tid & 15;                 // cols col0 + tx*4
    int ty = tid >> 4;                 // 0..7; rows ty + 8*i
    int row0 = blockIdx.x * BM;
    int col0 = blockIdx.y * BN;
    float acc[8][4] = {};
    for (int k0 = 0; k0 < K; k0 += KC) {
#pragma unroll
        for (int u = 0; u < 4; ++u) {
            int f4id = tid + 128 * u;
            int m = f4id >> 3;                 // 0..63
            int ks = (f4id & 7) * 4;           // 0,4,..28
            int r = row0 + m;
            float4 v = make_float4(0.f, 0.f, 0.f, 0.f);
            if (r < M) v = *(const float4*)&A[(size_t)r * K + k0 + ks];
            *(float4*)&As[m * LDA + ks] = v;
        }
#pragma unroll
        for (int u = 0; u < 4; ++u) {
            int f4id = tid + 128 * u;
            int kk = f4id >> 4;                // 0..31
            int n4 = (f4id & 15) * 4;          // 0..60
            *(float4*)&Bs[kk * BN + n4] =
                *(const float4*)&W[(size_t)(k0 + kk) * 128 + col0 + n4];
        }
        __syncthreads();
#pragma unroll
        for (int kc = 0; kc < KC; kc += 4) {
            float4 av[8], bv[4];
#pragma unroll
            for (int i = 0; i < 8; ++i)
                av[i] = *(const float4*)&As[(ty + 8 * i) * LDA + kc];
#pragma unroll
            for (int q = 0; q < 4; ++q)
                bv[q] = *(const float4*)&Bs[(kc + q) * BN + tx * 4];
#pragma unroll
            for (int q = 0; q < 4; ++q) {
#pragma unroll
                for (int i = 0; i < 8; ++i) {
                    float a = ((const float*)&av[i])[q];
                    acc[i][0] += a * bv[q].x;  acc[i][1] += a * bv[q].y;
                    acc[i][2] += a * bv[q].z;  acc[i][3] += a * bv[q].w;
                }
            }
        }
        __syncthreads();
    }
    int c0 = col0 + tx * 4;
#pragma unroll
    for (int i = 0; i < 8; ++i) {
        int r = row0 + ty + 8 * i;
        if (r < M) {
            float4 v0 = make_float4(acc[i][0], acc[i][1], acc[i][2], acc[i][3]);
            if (BIASRELU) {
                v0.x = fmaxf(v0.x + bias[c0], 0.f);   v0.y = fmaxf(v0.y + bias[c0+1], 0.f);
                v0.z = fmaxf(v0.z + bias[c0+2], 0.f); v0.w = fmaxf(v0.w + bias[c0+3], 0.f);
            }
            if (BF16OUT) {
                float dr = disv[r];
                uint2 o = make_uint2(bf16pair(dr * v0.x, dr * v0.y),
                                     bf16pair(dr * v0.z, dr * v0.w));
                ((uint2*)outp)[((size_t)r * 128 + c0) >> 2] = o;
            } else {
                *(float4*)&((float*)outp)[(size_t)r * 128 + c0] = v0;
            }
        }
    }
}

// ---------------------------------------------------------------------------
// K5a: F=128 aggregate over PRE-SCALED bf16 table (hb'[s] = dis[s]*h[s]).
// acc_i = dii*(sum_N hb'[s] + hb'[i]) + bias. uint2 lanes, 2 edges/inst.
template <bool RELU, bool BIAS, bool BF16OUT>
__global__ __launch_bounds__(256) void aggregate128b(const uint2* __restrict__ hb2,
                                                     const int* __restrict__ offsets,
                                                     const unsigned short* __restrict__ csr,
                                                     const float* __restrict__ dis,
                                                     const float* __restrict__ bias,
                                                     void* __restrict__ outp) {
    int wave = threadIdx.x >> 6;
    int lane = threadIdx.x & 63;
    int i = blockIdx.x * 4 + wave;
    if (i >= N_NODES) return;
    int sub = lane >> 5;              // which edge of the pair
    int q   = lane & 31;              // uint2 index within the 32-uint2 row
    float a0 = 0.f, a1 = 0.f, a2 = 0.f, a3 = 0.f;
    int j = offsets[i], s1 = offsets[i + 1];
    for (; j < s1; j += 16) {
        int s[8]; float m[8];
#pragma unroll
        for (int u = 0; u < 8; ++u) {
            int e = j + 2 * u + sub;
            bool valid = e < s1;
            s[u] = valid ? (int)csr[e] : 0;
            m[u] = valid ? 1.f : 0.f;
        }
        uint2 r[8];
#pragma unroll
        for (int u = 0; u < 8; ++u) r[u] = hb2[(size_t)s[u] * 32 + q];
#pragma unroll
        for (int u = 0; u < 8; ++u) {
            a0 += m[u] * bf16lo(r[u].x);
            a1 += m[u] * bf16hi(r[u].x);
            a2 += m[u] * bf16lo(r[u].y);
            a3 += m[u] * bf16hi(r[u].y);
        }
    }
    a0 += __shfl_xor(a0, 32, 64);
    a1 += __shfl_xor(a1, 32, 64);
    a2 += __shfl_xor(a2, 32, 64);
    a3 += __shfl_xor(a3, 32, 64);
    uint2 su = hb2[(size_t)i * 32 + q];     // self: weight 1 in scaled domain
    a0 += bf16lo(su.x);
    a1 += bf16hi(su.x);
    a2 += bf16lo(su.y);
    a3 += bf16hi(su.y);
    float dii = dis[i];
    a0 *= dii; a1 *= dii; a2 *= dii; a3 *= dii;
    if (BIAS) {
        float4 b = ((const float4*)bias)[q];    // features 4q..4q+3
        a0 += b.x; a1 += b.y; a2 += b.z; a3 += b.w;
    }
    if (RELU) {
        a0 = fmaxf(a0, 0.f); a1 = fmaxf(a1, 0.f);
        a2 = fmaxf(a2, 0.f); a3 = fmaxf(a3, 0.f);
    }
    if (sub == 0) {
        if (BF16OUT)   // next gather table: pre-scale by dis[i]
            ((uint2*)outp)[(size_t)i * 32 + q] =
                make_uint2(bf16pair(dii * a0, dii * a1), bf16pair(dii * a2, dii * a3));
        else
            ((float4*)outp)[(size_t)i * 32 + q] = make_float4(a0, a1, a2, a3);
    }
}

// K5b: F=64 aggregate over pre-scaled bf16 x-table. uint2 lanes, 4 edges/inst.
// Self term from fp32 x (exact): out = dii*sum + dii^2*x[i].
__global__ __launch_bounds__(256) void aggregate_xb(const uint2* __restrict__ xb2,
                                                    const float* __restrict__ x,
                                                    const int* __restrict__ offsets,
                                                    const unsigned short* __restrict__ csr,
                                                    const float* __restrict__ dis,
                                                    float* __restrict__ out) {
    int wave = threadIdx.x >> 6;
    int lane = threadIdx.x & 63;
    int i = blockIdx.x * 4 + wave;
    if (i >= N_NODES) return;
    int sub = lane >> 4;              // 0..3: which edge of the quad
    int q   = lane & 15;              // uint2 index within the 16-uint2 row
    float a0 = 0.f, a1 = 0.f, a2 = 0.f, a3 = 0.f;
    int j = offsets[i], s1 = offsets[i + 1];
    for (; j < s1; j += 32) {
        int s[8]; float m[8];
#pragma unroll
        for (int u = 0; u < 8; ++u) {
            int e = j + 4 * u + sub;
            bool valid = e < s1;
            s[u] = valid ? (int)csr[e] : 0;
            m[u] = valid ? 1.f : 0.f;
        }
        uint2 r[8];
#pragma unroll
        for (int u = 0; u < 8; ++u) r[u] = xb2[(size_t)s[u] * 16 + q];
#pragma unroll
        for (int u = 0; u < 8; ++u) {
            a0 += m[u] * bf16lo(r[u].x);
            a1 += m[u] * bf16hi(r[u].x);
            a2 += m[u] * bf16lo(r[u].y);
            a3 += m[u] * bf16hi(r[u].y);
        }
    }
    a0 += __shfl_xor(a0, 16, 64);  a1 += __shfl_xor(a1, 16, 64);
    a2 += __shfl_xor(a2, 16, 64);  a3 += __shfl_xor(a3, 16, 64);
    a0 += __shfl_xor(a0, 32, 64);  a1 += __shfl_xor(a1, 32, 64);
    a2 += __shfl_xor(a2, 32, 64);  a3 += __shfl_xor(a3, 32, 64);
    float dii = dis[i];
    float d2 = dii * dii;
    float4 sx = ((const float4*)x)[(size_t)i * 16 + q];   // self in fp32
    a0 = dii * a0 + d2 * sx.x;
    a1 = dii * a1 + d2 * sx.y;
    a2 = dii * a2 + d2 * sx.z;
    a3 = dii * a3 + d2 * sx.w;
    if (sub == 0) ((float4*)out)[(size_t)i * 16 + q] = make_float4(a0, a1, a2, a3);
}

// ---------------------------------------------------------------------------
// K6: mean-pool (batch is sorted -> register-accumulate 16 nodes, flush on change)
__global__ __launch_bounds__(128) void pool16(const float* __restrict__ h,
                                              const int* __restrict__ batch,
                                              float* __restrict__ g_acc,
                                              float* __restrict__ g_cnt) {
    const int NB = 16;
    int base = blockIdx.x * NB;
    int f = threadIdx.x;
    float acc = 0.f;
    int cur = -1, cnt = 0;
    for (int n = 0; n < NB; ++n) {
        int i = base + n;
        if (i >= N_NODES) break;
        int b = batch[i];
        if (b != cur) {
            if (cur >= 0) {
                atomicAdd(&g_acc[(size_t)cur * F_HID + f], acc);
                if (f == 0) atomicAdd(&g_cnt[cur], (float)cnt);
            }
            cur = b; acc = 0.f; cnt = 0;
        }
        acc += h[(size_t)i * F_HID + f];
        cnt++;
    }
    if (cur >= 0) {
        atomicAdd(&g_acc[(size_t)cur * F_HID + f], acc);
        if (f == 0) atomicAdd(&g_cnt[cur], (float)cnt);
    }
}

// ---------------------------------------------------------------------------
// K6b: g2 = (g_acc/cnt) @ W2 + b2   [256,128]@[128,128]  (layer-2 linear,
// commuted past aggregate+pool: pool(Â(hW2)+b2) == pool(Âh)W2 + b2)
__global__ __launch_bounds__(128) void graph_w2(const float* __restrict__ g_acc,
                                                const float* __restrict__ g_cnt,
                                                const float* __restrict__ W2,
                                                const float* __restrict__ b2,
                                                float* __restrict__ g2) {
    __shared__ float row[F_HID];
    int g = blockIdx.x;
    int t = threadIdx.x;              // 0..127
    float c = g_cnt[g];
    row[t] = g_acc[(size_t)g * F_HID + t] / fmaxf(c, 1.0f);
    __syncthreads();
    float acc = b2[t];
    for (int k = 0; k < F_HID; ++k) acc += row[k] * W2[(size_t)k * F_HID + t];
    g2[(size_t)g * F_HID + t] = acc;
}

// K7: g_hid = relu(g2 @ Wm1 + bm1)   [256,128]@[128,512]
__global__ __launch_bounds__(512) void mlp1(const float* __restrict__ g2,
                                            const float* __restrict__ Wm1,
                                            const float* __restrict__ bm1,
                                            float* __restrict__ g_hid) {
    __shared__ float row[F_HID];
    int g = blockIdx.x;
    int t = threadIdx.x;              // 0..511
    if (t < F_HID) row[t] = g2[(size_t)g * F_HID + t];
    __syncthreads();
    float acc = bm1[t];
    for (int k = 0; k < F_HID; ++k) acc += row[k] * Wm1[(size_t)k * N_HID + t];
    g_hid[(size_t)g * N_HID + t] = fmaxf(acc, 0.f);
}

// K8: out = g_hid @ Wm2 + bm2   [256,512]@[512,256]
__global__ __launch_bounds__(256) void mlp2(const float* __restrict__ g_hid,
                                            const float* __restrict__ Wm2,
                                            const float* __restrict__ bm2,
                                            float* __restrict__ out) {
    __shared__ float row[N_HID];
    int g = blockIdx.x;
    int t = threadIdx.x;              // 0..255
    row[t] = g_hid[(size_t)g * N_HID + t];
    row[t + 256] = g_hid[(size_t)g * N_HID + t + 256];
    __syncthreads();
    float acc = bm2[t];
    for (int k = 0; k < N_HID; ++k) acc += row[k] * Wm2[(size_t)k * N_OUT + t];
    out[(size_t)g * N_OUT + t] = acc;
}

// ---------------------------------------------------------------------------
extern "C" void kernel_launch(void* const* d_in, const int* in_sizes, int n_in,
                              void* d_out, int out_size, void* d_ws, size_t ws_size,
                              hipStream_t stream) {
    const float* x   = (const float*)d_in[0];
    const int* ei    = (const int*)d_in[1];     // [2, E] int32
    const int* batch = (const int*)d_in[2];
    const float* W0 = (const float*)d_in[3];  const float* b0 = (const float*)d_in[4];
    const float* W1 = (const float*)d_in[5];  const float* b1 = (const float*)d_in[6];
    const float* W2 = (const float*)d_in[7];  const float* b2 = (const float*)d_in[8];
    const float* Wm1 = (const float*)d_in[9];  const float* bm1 = (const float*)d_in[10];
    const float* Wm2 = (const float*)d_in[11]; const float* bm2 = (const float*)d_in[12];

    // bump allocator on d_ws, 256B-aligned slots
    char* p = (char*)d_ws;
    auto alloc = [&](size_t bytes) -> char* {
        char* r = p;
        p += (bytes + 255) & ~(size_t)255;
        return r;
    };
    // zero-init region (contiguous in allocation order)
    int*   indeg  = (int*)alloc(N_NODES * 4);
    int*   cursor = (int*)alloc(N_NODES * 4);
    float* g_acc  = (float*)alloc((size_t)N_GRAPHS * F_HID * 4);
    float* g_cnt  = (float*)alloc(N_GRAPHS * 4);
    size_t zero_bytes = (size_t)(p - (char*)indeg);
    // rest
    int*   blockSums = (int*)alloc(SCAN_NBLK * 4);
    int*   offsets = (int*)alloc((N_NODES + 1) * 4);
    float* dis     = (float*)alloc(N_NODES * 4);
    unsigned short* csr = (unsigned short*)alloc((size_t)N_EDGES * 2);
    unsigned int* xb     = (unsigned int*)alloc((size_t)N_NODES * F_IN / 2 * 4);   // bf16 x'
    float*        ax     = (float*)alloc((size_t)N_NODES * F_IN * 4);
    float*        h_a    = (float*)alloc((size_t)N_NODES * F_HID * 4);
    unsigned int* h_tmpb = (unsigned int*)alloc((size_t)N_NODES * F_HID / 2 * 4);  // bf16'
    unsigned int* h_bb   = (unsigned int*)alloc((size_t)N_NODES * F_HID / 2 * 4);  // bf16'
    float*        agg2   = (float*)alloc((size_t)N_NODES * F_HID * 4);
    float*        g2     = (float*)alloc((size_t)N_GRAPHS * F_HID * 4);
    float*        g_hid  = (float*)alloc((size_t)N_GRAPHS * N_HID * 4);
    (void)ws_size; (void)in_sizes; (void)n_in; (void)out_size;

    (void)hipMemsetAsync(indeg, 0, zero_bytes, stream);

    count_deg<<<(N_EDGES + 255) / 256, 256, 0, stream>>>(ei, indeg);
    scan_partial<<<SCAN_NBLK, SCAN_B, 0, stream>>>(indeg, blockSums);
    scan_block_sums<<<1, SCAN_B, 0, stream>>>(blockSums);
    scan_final<<<SCAN_NBLK, SCAN_B, 0, stream>>>(indeg, blockSums, offsets, dis);
    build_csr<<<(N_EDGES + 255) / 256, 256, 0, stream>>>(ei, offsets, cursor, csr);
    cvt_bf16<<<(N_NODES * F_IN / 4 + 255) / 256, 256, 0, stream>>>(x, dis, xb, N_NODES * F_IN / 4);

    int agg_grid = (N_NODES + 3) / 4;          // 4 nodes (waves) per block
    dim3 gemm_grid((N_NODES + 63) / 64, 2);    // 1564 blocks

    // layer 0 (reordered): ax = Â x (pre-scaled bf16 gather); h_a = relu(ax @ W0 + b0)
    aggregate_xb<<<agg_grid, 256, 0, stream>>>((const uint2*)xb, x, offsets, csr, dis, ax);
    gemm64<F_IN, true, false><<<gemm_grid, 128, 0, stream>>>(ax, W0, b0, nullptr, h_a, N_NODES);
    // layer 1: h_tmpb = bf16(dis * (h_a @ W1)); h_bb = bf16(dis * relu(Â... + b1))
    gemm64<F_HID, false, true><<<gemm_grid, 128, 0, stream>>>(h_a, W1, nullptr, dis, h_tmpb, N_NODES);
    aggregate128b<true, true, true><<<agg_grid, 256, 0, stream>>>((const uint2*)h_tmpb, offsets, csr, dis, b1, h_bb);
    // layer 2 (commuted): agg2 = Â h_bb (fp32 out); pool; then @W2 + b2
    aggregate128b<false, false, false><<<agg_grid, 256, 0, stream>>>((const uint2*)h_bb, offsets, csr, dis, nullptr, agg2);

    // pool + layer-2 linear + MLP
    pool16<<<(N_NODES + 15) / 16, 128, 0, stream>>>(agg2, batch, g_acc, g_cnt);
    graph_w2<<<N_GRAPHS, 128, 0, stream>>>(g_acc, g_cnt, W2, b2, g2);
    mlp1<<<N_GRAPHS, N_HID, 0, stream>>>(g2, Wm1, bm1, g_hid);
    mlp2<<<N_GRAPHS, N_OUT, 0, stream>>>(g_hid, Wm2, bm2, (float*)d_out);
}